// Round 11
// baseline (778.566 us; speedup 1.0000x reference)
//
#include <hip/hip_runtime.h>
#include <hip/hip_bf16.h>

#define KNN 20
#define NEG_SLOPE 0.2f

constexpr int BB = 8;
constexpr int NN = 1024;
constexpr int MM = 1024;

typedef short bf16x8 __attribute__((ext_vector_type(8)));
typedef float f32x4 __attribute__((ext_vector_type(4)));

// ---------------- transpose f32: (B,C,Np) -> (B,Np,C) ----------------
__global__ __launch_bounds__(256) void k_transpose(
    const float* __restrict__ in, float* __restrict__ out, int C, int Np) {
  int total = BB * C * Np;
  for (int t = blockIdx.x * 256 + threadIdx.x; t < total; t += gridDim.x * 256) {
    int c = t % C;
    int n = (t / C) % Np;
    int b = t / (C * Np);
    out[t] = in[((size_t)b * C + c) * Np + n];
  }
}

// ---------------- f32 -> bf16 convert ----------------
__global__ __launch_bounds__(256) void k_cvt_bf16(
    const float* __restrict__ in, __hip_bfloat16* __restrict__ out, int n) {
  int i = blockIdx.x * 256 + threadIdx.x;
  if (i < n) out[i] = __float2bfloat16(in[i]);
}

// ------- per-point squared norm (RECIP=0) or reciprocal norm (RECIP=1), f64 out -------
template <int RECIP>
__global__ __launch_bounds__(256) void k_rowsq(
    const float* __restrict__ A, int ld, int C, double* __restrict__ sq) {
  int p = blockIdx.x * 256 + threadIdx.x;
  if (p >= BB * NN) return;
  const float* row = A + (size_t)p * ld;
  double s = 0.0;
  for (int c = 0; c < C; ++c) { double v = (double)row[c]; s += v * v; }
  if (RECIP) {
    sq[p] = 1.0 / fmax(sqrt(s), 1e-12);
  } else {
    sq[p] = s;
  }
}

// ---- fused L1 knn (C=3): all points in LDS, f64 distances in-register, topk direct ----
__global__ __launch_bounds__(256) void k_knn3(
    const float* __restrict__ xs3, const double* __restrict__ sq, int* __restrict__ idx) {
  __shared__ float P[NN * 3];
  int b = blockIdx.x;
  const float* Xb = xs3 + (size_t)b * NN * 3;
  int tid = threadIdx.x;
  for (int t = tid; t < NN * 3; t += 256) P[t] = Xb[t];
  __syncthreads();
  int wave = tid >> 6, lane = tid & 63;
  int i = blockIdx.y * 4 + wave;
  double xi = (double)P[i * 3], yi = (double)P[i * 3 + 1], zi = (double)P[i * 3 + 2];
  double sqi = sq[b * NN + i];
  double v[16];
#pragma unroll
  for (int m = 0; m < 16; ++m) {
    int j = m * 64 + lane;
    double d = fma(xi, (double)P[j * 3], 0.0);
    d = fma(yi, (double)P[j * 3 + 1], d);
    d = fma(zi, (double)P[j * 3 + 2], d);
    v[m] = 2.0 * d - sqi - sq[b * NN + j];
  }
  int* op = idx + ((size_t)b * NN + i) * KNN;
  for (int r = 0; r < KNN; ++r) {
    double bv = -INFINITY;
    int bj = MM;
#pragma unroll
    for (int m = 0; m < 16; ++m) {
      if (v[m] > bv) { bv = v[m]; bj = m * 64 + lane; }
    }
#pragma unroll
    for (int off = 32; off > 0; off >>= 1) {
      double ov = __shfl_xor(bv, off, 64);
      int oj = __shfl_xor(bj, off, 64);
      if (ov > bv || (ov == bv && oj < bj)) { bv = ov; bj = oj; }
    }
    if (bj < MM && lane == (bj & 63)) v[bj >> 6] = -INFINITY;
    if (lane == 0) op[r] = bj;
  }
}

// ---- f64 gram: 128(i)x64(j) tiles, 8x4/thread, conflict-free strided-j, 1024 blocks ----
// MODE 1: D = 2*dot - sqA_i - sqB_j ; MODE 2: D = dot * rnA_i * rnB_j
template <int MODE>
__global__ __launch_bounds__(256) void k_gram2(
    const float* __restrict__ A, int lda, const float* __restrict__ Bm, int ldb,
    const double* __restrict__ sqA, const double* __restrict__ sqB,
    double* __restrict__ D, int C, int b0) {
  __shared__ double As[16][136];
  __shared__ double Bs[16][72];
  int bg = b0 + blockIdx.x;
  int bl = blockIdx.x;
  int j0 = blockIdx.y * 64;
  int i0 = blockIdx.z * 128;
  const float* Ab = A + (size_t)bg * NN * lda;
  const float* Bb = Bm + (size_t)bg * MM * ldb;
  int tx = threadIdx.x, ty = threadIdx.y;
  int tid = ty * 16 + tx;
  double acc[8][4] = {};
  for (int c0 = 0; c0 < C; c0 += 16) {
    for (int r = 0; r < 2; ++r) {
      int li = tid + r * 256;
      int row = li >> 2;
      int f = (li & 3) * 4;
      float4 av = *(const float4*)&Ab[(size_t)(i0 + row) * lda + c0 + f];
      As[f + 0][row] = (double)av.x;
      As[f + 1][row] = (double)av.y;
      As[f + 2][row] = (double)av.z;
      As[f + 3][row] = (double)av.w;
    }
    {
      int row = tid >> 2;
      int f = (tid & 3) * 4;
      float4 bv = *(const float4*)&Bb[(size_t)(j0 + row) * ldb + c0 + f];
      Bs[f + 0][row] = (double)bv.x;
      Bs[f + 1][row] = (double)bv.y;
      Bs[f + 2][row] = (double)bv.z;
      Bs[f + 3][row] = (double)bv.w;
    }
    __syncthreads();
#pragma unroll
    for (int k = 0; k < 16; ++k) {
      double a_[8], b_[4];
#pragma unroll
      for (int ii = 0; ii < 8; ++ii) a_[ii] = As[k][ty * 8 + ii];
#pragma unroll
      for (int jj = 0; jj < 4; ++jj) b_[jj] = Bs[k][jj * 16 + tx];
#pragma unroll
      for (int ii = 0; ii < 8; ++ii)
#pragma unroll
        for (int jj = 0; jj < 4; ++jj)
          acc[ii][jj] = fma(a_[ii], b_[jj], acc[ii][jj]);
    }
    __syncthreads();
  }
  for (int ii = 0; ii < 8; ++ii) {
    int i = i0 + ty * 8 + ii;
    for (int jj = 0; jj < 4; ++jj) {
      int j = j0 + jj * 16 + tx;
      double r = acc[ii][jj];
      if (MODE == 1) r = 2.0 * r - sqA[bg * NN + i] - sqB[bg * NN + j];
      if (MODE == 2) r = r * sqA[bg * NN + i] * sqB[bg * NN + j];
      D[((size_t)bl * NN + i) * MM + j] = r;
    }
  }
}

// ------- symmetric euclidean gram (A==B): triangular blocks, strided-j mapping -------
__global__ __launch_bounds__(256) void k_gram_sym(
    const float* __restrict__ A, int lda, const double* __restrict__ sqA,
    double* __restrict__ D, int C, int b0) {
  __shared__ double As[16][68];
  __shared__ double Bs[16][68];
  __shared__ double T[64][65];
  int p = blockIdx.y;  // 0..135 triangular pair index
  int r = (int)((sqrtf(8.f * p + 1.f) - 1.f) * 0.5f);
  while ((r + 1) * (r + 2) / 2 <= p) ++r;
  while (r * (r + 1) / 2 > p) --r;
  int cc = p - r * (r + 1) / 2;
  int i0 = r * 64, j0 = cc * 64;
  int bg = b0 + blockIdx.x;
  int bl = blockIdx.x;
  const float* Ab = A + (size_t)bg * NN * lda;
  int tx = threadIdx.x, ty = threadIdx.y;
  int tid = ty * 16 + tx;
  double acc[4][4] = {};
  for (int c0 = 0; c0 < C; c0 += 16) {
    for (int rr = 0; rr < 4; ++rr) {
      int li = tid + rr * 256;
      int row = li >> 4, k = li & 15;
      int c = c0 + k;
      As[k][row] = (c < C) ? (double)Ab[(size_t)(i0 + row) * lda + c] : 0.0;
      Bs[k][row] = (c < C) ? (double)Ab[(size_t)(j0 + row) * lda + c] : 0.0;
    }
    __syncthreads();
#pragma unroll
    for (int k = 0; k < 16; ++k) {
      double a_[4], b_[4];
#pragma unroll
      for (int ii = 0; ii < 4; ++ii) a_[ii] = As[k][ty * 4 + ii];
#pragma unroll
      for (int jj = 0; jj < 4; ++jj) b_[jj] = Bs[k][jj * 16 + tx];
#pragma unroll
      for (int ii = 0; ii < 4; ++ii)
#pragma unroll
        for (int jj = 0; jj < 4; ++jj)
          acc[ii][jj] = fma(a_[ii], b_[jj], acc[ii][jj]);
    }
    __syncthreads();
  }
  for (int ii = 0; ii < 4; ++ii) {
    int i = i0 + ty * 4 + ii;
    for (int jj = 0; jj < 4; ++jj) {
      int j = j0 + jj * 16 + tx;
      double v = 2.0 * acc[ii][jj] - sqA[bg * NN + i] - sqA[bg * NN + j];
      D[((size_t)bl * NN + i) * MM + j] = v;
      T[jj * 16 + tx][ty * 4 + ii] = v;
    }
  }
  if (i0 != j0) {
    __syncthreads();
    for (int rr = 0; rr < 16; ++rr) {
      int li = tid + rr * 256;
      int jrow = li >> 6, il = li & 63;
      D[((size_t)bl * NN + j0 + jrow) * MM + i0 + il] = T[jrow][il];
    }
  }
}

// ------- top-20 per row, f64; grid (batch, rowblock) for XCD L2 affinity -------
__global__ __launch_bounds__(256) void k_topk(const double* __restrict__ D,
                                              int* __restrict__ idx, int b0) {
  int wave = threadIdx.x >> 6;
  int lane = threadIdx.x & 63;
  int bl = blockIdx.x;
  int row = blockIdx.y * 4 + wave;
  const double* rp = D + ((size_t)bl * NN + row) * MM;
  double v[16];
#pragma unroll
  for (int m = 0; m < 16; ++m) v[m] = rp[m * 64 + lane];
  int* op = idx + ((size_t)(b0 + bl) * NN + row) * KNN;
  for (int r = 0; r < KNN; ++r) {
    double bv = -INFINITY;
    int bj = MM;
#pragma unroll
    for (int m = 0; m < 16; ++m) {
      if (v[m] > bv) { bv = v[m]; bj = m * 64 + lane; }
    }
#pragma unroll
    for (int off = 32; off > 0; off >>= 1) {
      double ov = __shfl_xor(bv, off, 64);
      int oj = __shfl_xor(bj, off, 64);
      if (ov > bv || (ov == bv && oj < bj)) { bv = ov; bj = oj; }
    }
    if (bj < MM && lane == (bj & 63)) v[bj >> 6] = -INFINITY;
    if (lane == 0) op[r] = bj;
  }
}

// ------- per-point feature matmul (64x64 tile): batch = blockIdx.x (XCD affinity) -------
// mode 0: weff = w[o,c]; mode 1: weff = w[o,C+c] - w[o,c]
__global__ __launch_bounds__(256) void k_featmm(
    const float* __restrict__ src, int lds_, const float* __restrict__ w, int CW,
    float* __restrict__ out, int C, int O, int mode, int Np) {
  __shared__ float As[16][68];
  __shared__ float Ws[16][68];
  int b = blockIdx.x;
  int o0 = blockIdx.y * 64;
  int j0 = blockIdx.z * 64;
  int tx = threadIdx.x, ty = threadIdx.y;
  int tid = ty * 16 + tx;
  const float* Sb = src + (size_t)b * Np * lds_;
  float acc[4][4] = {};
  for (int c0 = 0; c0 < C; c0 += 16) {
    for (int r = 0; r < 4; ++r) {
      int li = tid + r * 256;
      int row = li >> 4, k = li & 15;
      int c = c0 + k;
      As[k][row] = (c < C) ? Sb[(size_t)(j0 + row) * lds_ + c] : 0.f;
      float wv = 0.f;
      if (c < C) {
        const float* wr = w + (size_t)(o0 + row) * CW;
        wv = mode == 0 ? wr[c] : (wr[C + c] - wr[c]);
      }
      Ws[k][row] = wv;
    }
    __syncthreads();
#pragma unroll
    for (int k = 0; k < 16; ++k) {
      float a_[4], b_[4];
#pragma unroll
      for (int ii = 0; ii < 4; ++ii) a_[ii] = As[k][ty * 4 + ii];
#pragma unroll
      for (int jj = 0; jj < 4; ++jj) b_[jj] = Ws[k][tx * 4 + jj];
#pragma unroll
      for (int ii = 0; ii < 4; ++ii)
#pragma unroll
        for (int jj = 0; jj < 4; ++jj)
          acc[ii][jj] = fmaf(a_[ii], b_[jj], acc[ii][jj]);
    }
    __syncthreads();
  }
  for (int ii = 0; ii < 4; ++ii) {
    int j = j0 + ty * 4 + ii;
    float4 v;
    float* vp = &v.x;
    for (int jj = 0; jj < 4; ++jj) vp[jj] = acc[ii][jj];
    *(float4*)&out[((size_t)b * Np + j) * O + o0 + tx * 4] = v;
  }
}

// ---- layer-5 GEMM via bf16 MFMA: per-wave 16x16 tile, frags direct from global ----
// A[m][k]: m=lane&15 (j), k=quad*8+j'  ;  B[k][n]: n=lane&15 (o), k=quad*8+j'
// C/D: col(=o)=lane&15, row(=j)=quad*4+reg
__global__ __launch_bounds__(256) void k_gemm5_mfma(
    const __hip_bfloat16* __restrict__ cath, const __hip_bfloat16* __restrict__ w5h,
    float* __restrict__ out) {
  int b = blockIdx.x;
  int j0 = blockIdx.y * 16;
  int o0 = blockIdx.z * 64 + (threadIdx.x >> 6) * 16;
  int lane = threadIdx.x & 63;
  int m = lane & 15;
  int quad = lane >> 4;
  const __hip_bfloat16* arow = cath + ((size_t)b * NN + j0 + m) * 512 + quad * 8;
  const __hip_bfloat16* brow = w5h + (size_t)(o0 + m) * 512 + quad * 8;
  f32x4 acc = {0.f, 0.f, 0.f, 0.f};
#pragma unroll
  for (int c0 = 0; c0 < 512; c0 += 32) {
    bf16x8 a = *(const bf16x8*)(arow + c0);
    bf16x8 bb = *(const bf16x8*)(brow + c0);
    acc = __builtin_amdgcn_mfma_f32_16x16x32_bf16(a, bb, acc, 0, 0, 0);
  }
  float* obase = &out[((size_t)b * NN + j0 + quad * 4) * 512 + o0 + m];
#pragma unroll
  for (int r = 0; r < 4; ++r) obase[(size_t)r * 512] = acc[r];
}

// ------- fused gather: per (n,o) compute max_k y, accumulate BN stats; b = blockIdx.x -------
__global__ __launch_bounds__(256) void k_gather(
    const float* __restrict__ u, const float* __restrict__ t, const int* __restrict__ idx,
    double* __restrict__ stats, float* __restrict__ mx, int O, int srcNp) {
  __shared__ int lidx[16 * KNN];
  __shared__ double rs[256];
  __shared__ double rq[256];
  int b = blockIdx.x;
  int n0 = blockIdx.y * 16;
  int o0 = blockIdx.z * 64;
  int tid = threadIdx.x;
  int lane = tid & 63, nsl = tid >> 6;
  for (int w = tid; w < 16 * KNN; w += 256)
    lidx[w] = idx[((size_t)b * NN + n0) * KNN + w];
  __syncthreads();
  int oo = o0 + lane;
  double s1 = 0.0, s2 = 0.0;
  for (int ns = nsl; ns < 16; ns += 4) {
    size_t row = (size_t)b * NN + n0 + ns;
    float tv = t[row * O + oo];
    float mxv = -INFINITY, a1 = 0.f, a2 = 0.f;
#pragma unroll
    for (int k = 0; k < KNN; ++k) {
      int j = lidx[ns * KNN + k];
      float yv = u[((size_t)b * srcNp + j) * O + oo] + tv;
      mxv = fmaxf(mxv, yv);
      a1 += yv;
      a2 = fmaf(yv, yv, a2);
    }
    mx[row * O + oo] = mxv;
    s1 += (double)a1;
    s2 += (double)a2;
  }
  rs[tid] = s1;
  rq[tid] = s2;
  __syncthreads();
  if (tid < 64) {
    s1 = rs[tid] + rs[tid + 64] + rs[tid + 128] + rs[tid + 192];
    s2 = rq[tid] + rq[tid + 64] + rq[tid + 128] + rq[tid + 192];
    atomicAdd(&stats[o0 + tid], s1);
    atomicAdd(&stats[O + o0 + tid], s2);
  }
}

// ---------------- fold BN into per-channel scale/shift ----------------
__global__ void k_bnfin(const double* __restrict__ stats, const float* __restrict__ gamma,
                        const float* __restrict__ beta, float* __restrict__ sc,
                        int O, double cnt) {
  int o = threadIdx.x;
  if (o >= O) return;
  double mean = stats[o] / cnt;
  double var = stats[O + o] / cnt - mean * mean;
  if (var < 0.0) var = 0.0;
  double rstd = 1.0 / sqrt(var + 1e-5);
  float s = gamma[o] * (float)rstd;
  float c = beta[o] - (float)mean * s;
  sc[o] = s;
  sc[O + o] = c;
}

// --- apply BN+lrelu to stored max, write cat slice (f32 + bf16 mirror for L5 MFMA) ---
__global__ __launch_bounds__(256) void k_bnapply(
    const float* __restrict__ mx, const float* __restrict__ u, const float* __restrict__ t,
    const int* __restrict__ idx, const float* __restrict__ sc, float* __restrict__ cat,
    __hip_bfloat16* __restrict__ cath, int coff, int O, int srcNp) {
  int i = blockIdx.x * 256 + threadIdx.x;
  int total = BB * NN * O;
  if (i >= total) return;
  int oo = i % O;
  int n = (i / O) % NN;
  int b = i / (O * NN);
  float s = sc[oo], c = sc[O + oo];
  float v;
  if (s >= 0.f) {
    v = mx[i];
  } else {  // monotone-decreasing transform needs min_k y (never hit with gamma=1)
    float tv = t[i];
    float mn = INFINITY;
    for (int k = 0; k < KNN; ++k) {
      int j = idx[((size_t)b * NN + n) * KNN + k];
      mn = fminf(mn, u[((size_t)b * srcNp + j) * O + oo] + tv);
    }
    v = mn;
  }
  float a = s * v + c;
  a = (a >= 0.f) ? a : NEG_SLOPE * a;
  size_t oidx = ((size_t)b * NN + n) * 512 + coff + oo;
  cat[oidx] = a;
  cath[oidx] = __float2bfloat16(a);
}

// ------- layer 5 streaming stats over stored y5 (B,N,512) -------
__global__ __launch_bounds__(256) void k_stats512(
    const float* __restrict__ y5, double* __restrict__ stats) {
  int b = blockIdx.y;
  int n0 = blockIdx.x * 32;
  int tid = threadIdx.x;
  for (int part = 0; part < 2; ++part) {
    int oo = tid + part * 256;
    float a1 = 0.f, a2 = 0.f;
    for (int ns = 0; ns < 32; ++ns) {
      float v = y5[((size_t)b * NN + n0 + ns) * 512 + oo];
      a1 += v;
      a2 = fmaf(v, v, a2);
    }
    atomicAdd(&stats[oo], (double)a1);
    atomicAdd(&stats[512 + oo], (double)a2);
  }
}

// ------- layer 5 streaming finalize: BN+lrelu on stored y5, transpose, f32 store -------
__global__ __launch_bounds__(256) void k_final5b(
    const float* __restrict__ y5, const float* __restrict__ sc, float* __restrict__ out) {
  __shared__ float tile[64][65];
  int b = blockIdx.z;
  int n0 = blockIdx.x * 64;
  int o0 = blockIdx.y * 64;
  int tid = threadIdx.x;
  for (int r = 0; r < 16; ++r) {
    int li = tid + r * 256;
    int nl = li >> 6, ol = li & 63;
    float v = y5[((size_t)b * NN + n0 + nl) * 512 + o0 + ol];
    float a = sc[o0 + ol] * v + sc[512 + o0 + ol];
    a = (a >= 0.f) ? a : NEG_SLOPE * a;
    tile[nl][ol] = a;
  }
  __syncthreads();
  for (int r = 0; r < 16; ++r) {
    int li = tid + r * 256;
    int ol = li >> 6, nl = li & 63;
    out[((size_t)b * 512 + o0 + ol) * NN + n0 + nl] = tile[nl][ol];
  }
}

// ------- fallback layer 5 (CB<2): GEMM+stats recompute pass -------
__global__ __launch_bounds__(256) void k_mmstats(
    const float* __restrict__ src, const float* __restrict__ w,
    double* __restrict__ stats) {
  __shared__ float As[16][68];
  __shared__ float Ws[16][68];
  __shared__ float redS[16][64];
  __shared__ float redQ[16][64];
  int b = blockIdx.z;
  int j0 = blockIdx.y * 64;
  int o0 = blockIdx.x * 64;
  int tx = threadIdx.x, ty = threadIdx.y;
  int tid = ty * 16 + tx;
  const float* Sb = src + (size_t)b * NN * 512;
  float acc[4][4] = {};
  for (int c0 = 0; c0 < 512; c0 += 16) {
    for (int r = 0; r < 4; ++r) {
      int li = tid + r * 256;
      int row = li >> 4, k = li & 15;
      As[k][row] = Sb[(size_t)(j0 + row) * 512 + c0 + k];
      Ws[k][row] = w[(size_t)(o0 + row) * 512 + c0 + k];
    }
    __syncthreads();
#pragma unroll
    for (int k = 0; k < 16; ++k) {
      float a_[4], b_[4];
#pragma unroll
      for (int ii = 0; ii < 4; ++ii) a_[ii] = As[k][ty * 4 + ii];
#pragma unroll
      for (int jj = 0; jj < 4; ++jj) b_[jj] = Ws[k][tx * 4 + jj];
#pragma unroll
      for (int ii = 0; ii < 4; ++ii)
#pragma unroll
        for (int jj = 0; jj < 4; ++jj)
          acc[ii][jj] = fmaf(a_[ii], b_[jj], acc[ii][jj]);
    }
    __syncthreads();
  }
  for (int jj = 0; jj < 4; ++jj) {
    float s = 0.f, q = 0.f;
    for (int ii = 0; ii < 4; ++ii) { float v = acc[ii][jj]; s += v; q += v * v; }
    redS[ty][tx * 4 + jj] = s;
    redQ[ty][tx * 4 + jj] = q;
  }
  __syncthreads();
  if (tid < 64) {
    float s = 0.f, q = 0.f;
    for (int r = 0; r < 16; ++r) { s += redS[r][tid]; q += redQ[r][tid]; }
    atomicAdd(&stats[o0 + tid], (double)s);
    atomicAdd(&stats[512 + o0 + tid], (double)q);
  }
}

// ------- fallback layer 5 (CB<2): recompute GEMM, BN+lrelu, transposed store -------
__global__ __launch_bounds__(256) void k_final5(
    const float* __restrict__ src, const float* __restrict__ w,
    const float* __restrict__ sc, float* __restrict__ out) {
  __shared__ float As[16][68];
  __shared__ float Ws[16][68];
  __shared__ float tile[64][65];
  int b = blockIdx.z;
  int j0 = blockIdx.y * 64;
  int o0 = blockIdx.x * 64;
  int tx = threadIdx.x, ty = threadIdx.y;
  int tid = ty * 16 + tx;
  const float* Sb = src + (size_t)b * NN * 512;
  float acc[4][4] = {};
  for (int c0 = 0; c0 < 512; c0 += 16) {
    for (int r = 0; r < 4; ++r) {
      int li = tid + r * 256;
      int row = li >> 4, k = li & 15;
      As[k][row] = Sb[(size_t)(j0 + row) * 512 + c0 + k];
      Ws[k][row] = w[(size_t)(o0 + row) * 512 + c0 + k];
    }
    __syncthreads();
#pragma unroll
    for (int k = 0; k < 16; ++k) {
      float a_[4], b_[4];
#pragma unroll
      for (int ii = 0; ii < 4; ++ii) a_[ii] = As[k][ty * 4 + ii];
#pragma unroll
      for (int jj = 0; jj < 4; ++jj) b_[jj] = Ws[k][tx * 4 + jj];
#pragma unroll
      for (int ii = 0; ii < 4; ++ii)
#pragma unroll
        for (int jj = 0; jj < 4; ++jj)
          acc[ii][jj] = fmaf(a_[ii], b_[jj], acc[ii][jj]);
    }
    __syncthreads();
  }
  for (int ii = 0; ii < 4; ++ii)
    for (int jj = 0; jj < 4; ++jj) {
      int nl = ty * 4 + ii, ol = tx * 4 + jj;
      float a = sc[o0 + ol] * acc[ii][jj] + sc[512 + o0 + ol];
      a = (a >= 0.f) ? a : NEG_SLOPE * a;
      tile[nl][ol] = a;
    }
  __syncthreads();
  for (int r = 0; r < 16; ++r) {
    int li = tid + r * 256;
    int ol = li >> 6, nl = li & 63;
    out[((size_t)b * 512 + o0 + ol) * NN + j0 + nl] = tile[nl][ol];
  }
}

// =====================================================================================
// r11: layer-5 GEMM -> bf16 MFMA (16x16x32, f32 acc, frags direct from global; L5 has
// no KNN consumer so bf16 rounding is safe — KNN-feeding layers stay f32/f64).
// k_bnapply writes a bf16 mirror of cat; w5 converted once. Rest unchanged from r10.
extern "C" void kernel_launch(void* const* d_in, const int* in_sizes, int n_in,
                              void* d_out, int out_size, void* d_ws, size_t ws_size,
                              hipStream_t stream) {
  const float* x = (const float*)d_in[0];
  const float* y = (const float*)d_in[1];
  const float* w1 = (const float*)d_in[2];
  const float* w2 = (const float*)d_in[3];
  const float* w3 = (const float*)d_in[4];
  const float* w4 = (const float*)d_in[5];
  const float* w5 = (const float*)d_in[6];
  const float* g1 = (const float*)d_in[7];
  const float* b1 = (const float*)d_in[8];
  const float* g2 = (const float*)d_in[9];
  const float* b2 = (const float*)d_in[10];
  const float* g3 = (const float*)d_in[11];
  const float* b3 = (const float*)d_in[12];
  const float* g4 = (const float*)d_in[13];
  const float* b4 = (const float*)d_in[14];
  const float* g5 = (const float*)d_in[15];
  const float* b5 = (const float*)d_in[16];

  char* base = (char*)d_ws;
  size_t off = 0;
  auto alloc = [&](size_t bytes) -> char* {
    char* p = base + off;
    off += (bytes + 255) & ~(size_t)255;
    return p;
  };
  double* st = (double*)alloc(1024 * 8);
  float* sc  = (float*)alloc(1024 * 4);
  double* sq  = (double*)alloc((size_t)BB * NN * 8);
  double* rnx = (double*)alloc((size_t)BB * NN * 8);
  double* rny = (double*)alloc((size_t)BB * MM * 8);
  int*   idxb = (int*)alloc((size_t)BB * NN * KNN * 4);
  float* xs3 = (float*)alloc((size_t)BB * NN * 3 * 4);
  float* ys  = (float*)alloc((size_t)BB * MM * 128 * 4);
  float* cat = (float*)alloc((size_t)BB * NN * 512 * 4);
  __hip_bfloat16* cath = (__hip_bfloat16*)alloc((size_t)BB * NN * 512 * 2);
  __hip_bfloat16* w5h  = (__hip_bfloat16*)alloc((size_t)512 * 512 * 2);
  size_t ddBatchBytes = (size_t)NN * MM * 8;  // 8 MB per batch (f64)
  size_t avail = (ws_size > off) ? (ws_size - off) : 0;
  int CB = (int)(avail / ddBatchBytes);
  if (CB < 1) CB = 1;
  if (CB > BB) CB = BB;
  char*  U   = alloc((size_t)CB * ddBatchBytes);
  double* DD = (double*)U;                     // dist/simi chunk (f64), dead after topk
  float* tt  = (float*)U;                      // center term (f32, <=8MB), after DD dead
  float* y5  = (float*)U;                      // layer-5 pre-BN (16MB, needs CB>=2)
  float* uu  = (float*)d_out;                  // source term (<=8MB)
  float* mx  = (float*)d_out + (size_t)2 * 1024 * 1024;  // max_k y (<=8MB)
  float* outp = (float*)d_out;

  const dim3 blk2(16, 16);
  const double cntE = (double)BB * NN * KNN;

  // knn: sym=1 -> triangular symmetric euclid gram (A==B); else general 128x64 MODE
  auto knn = [&](const float* A, int lda, const float* Bm, int ldb,
                 const double* sa, const double* sb, int C, int mode, int sym) {
    for (int b0 = 0; b0 < BB; b0 += CB) {
      int cb = (BB - b0 < CB) ? (BB - b0) : CB;
      if (sym) {
        k_gram_sym<<<dim3(cb, 136), blk2, 0, stream>>>(A, lda, sa, DD, C, b0);
      } else {
        dim3 g(cb, MM / 64, NN / 128);
        if (mode == 1) k_gram2<1><<<g, blk2, 0, stream>>>(A, lda, Bm, ldb, sa, sb, DD, C, b0);
        else           k_gram2<2><<<g, blk2, 0, stream>>>(A, lda, Bm, ldb, sa, sb, DD, C, b0);
      }
      k_topk<<<dim3(cb, 256), 256, 0, stream>>>(DD, idxb, b0);
    }
  };

  auto edge_layer = [&](const float* ctr, int ldc, const float* src, int ldsrc, int srcNp,
                        const float* w, int CW, const float* g, const float* bb,
                        int C, int O, int coff) {
    k_featmm<<<dim3(8, O / 64, 16), blk2, 0, stream>>>(src, ldsrc, w, CW, uu, C, O, 0, srcNp);
    k_featmm<<<dim3(8, O / 64, 16), blk2, 0, stream>>>(ctr, ldc, w, CW, tt, C, O, 1, NN);
    hipMemsetAsync(st, 0, 1024 * 8, stream);
    k_gather<<<dim3(BB, NN / 16, O / 64), 256, 0, stream>>>(uu, tt, idxb, st, mx, O, srcNp);
    k_bnfin<<<1, O, 0, stream>>>(st, g, bb, sc, O, cntE);
    k_bnapply<<<(BB * NN * O + 255) / 256, 256, 0, stream>>>(mx, uu, tt, idxb, sc, cat,
                                                             cath, coff, O, srcNp);
  };

  // ---- input transposes + w5 bf16 convert ----
  k_transpose<<<96, 256, 0, stream>>>(x, xs3, 3, NN);
  k_transpose<<<2048, 256, 0, stream>>>(y, ys, 128, MM);
  k_cvt_bf16<<<1024, 256, 0, stream>>>(w5, w5h, 512 * 512);

  // ---- layer 1: C=3, O=64 (fused knn, no DD) ----
  k_rowsq<0><<<32, 256, 0, stream>>>(xs3, 3, 3, sq);
  k_knn3<<<dim3(BB, 256), 256, 0, stream>>>(xs3, sq, idxb);
  edge_layer(xs3, 3, xs3, 3, NN, w1, 6, g1, b1, 3, 64, 0);

  // ---- layer 2: x1 = cat[:,0:64], C=64, O=64 ----
  k_rowsq<0><<<32, 256, 0, stream>>>(cat, 512, 64, sq);
  knn(cat, 512, cat, 512, sq, sq, 64, 1, 1);
  edge_layer(cat, 512, cat, 512, NN, w2, 128, g2, b2, 64, 64, 64);

  // ---- layer 3: x2 = cat[:,64:128], C=64, O=128 ----
  k_rowsq<0><<<32, 256, 0, stream>>>(cat + 64, 512, 64, sq);
  knn(cat + 64, 512, cat + 64, 512, sq, sq, 64, 1, 1);
  edge_layer(cat + 64, 512, cat + 64, 512, NN, w3, 128, g3, b3, 64, 128, 128);

  // ---- layer 4 (IA): x3 = cat[:,128:256], src = y (cosine knn), C=128, O=256 ----
  k_rowsq<1><<<32, 256, 0, stream>>>(cat + 128, 512, 128, rnx);
  k_rowsq<1><<<32, 256, 0, stream>>>(ys, 128, 128, rny);
  knn(cat + 128, 512, ys, 128, rnx, rny, 128, 2, 0);
  edge_layer(cat + 128, 512, ys, 128, MM, w4, 256, g4, b4, 128, 256, 256);

  // ---- layer 5: bf16-MFMA GEMM -> y5, BN over (B,N), lrelu, transposed out ----
  hipMemsetAsync(st, 0, 1024 * 8, stream);
  if (CB >= 2) {
    k_gemm5_mfma<<<dim3(BB, 64, 8), 256, 0, stream>>>(cath, w5h, y5);
    k_stats512<<<dim3(32, 8), 256, 0, stream>>>(y5, st);
    k_bnfin<<<1, 512, 0, stream>>>(st, g5, b5, sc, 512, (double)(BB * NN));
    k_final5b<<<dim3(16, 8, 8), 256, 0, stream>>>(y5, sc, outp);
  } else {
    k_mmstats<<<dim3(8, 16, 8), blk2, 0, stream>>>(cat, w5, st);
    k_bnfin<<<1, 512, 0, stream>>>(st, g5, b5, sc, 512, (double)(BB * NN));
    k_final5<<<dim3(8, 16, 8), blk2, 0, stream>>>(cat, w5, sc, outp);
  }
}

// Round 12
// 694.881 us; speedup vs baseline: 1.1204x; 1.1204x over previous
//
#include <hip/hip_runtime.h>
#include <hip/hip_bf16.h>

#define KNN 20
#define NEG_SLOPE 0.2f

constexpr int BB = 8;
constexpr int NN = 1024;
constexpr int MM = 1024;

typedef short bf16x8 __attribute__((ext_vector_type(8)));
typedef float f32x4 __attribute__((ext_vector_type(4)));

// ================= top-20 selection (set-exact) =================
// Exact f64 reference path (jax tie semantics: larger value, tie -> lower idx).
__device__ __forceinline__ void topk_exact_f64(double (&v)[16], int lane, int* op) {
  for (int r = 0; r < KNN; ++r) {
    double bv = -INFINITY;
    int bj = MM;
#pragma unroll
    for (int m = 0; m < 16; ++m) {
      if (v[m] > bv) { bv = v[m]; bj = m * 64 + lane; }
    }
#pragma unroll
    for (int off = 32; off > 0; off >>= 1) {
      double ov = __shfl_xor(bv, off, 64);
      int oj = __shfl_xor(bj, off, 64);
      if (ov > bv || (ov == bv && oj < bj)) { bv = ov; bj = oj; }
    }
    if (bj < MM && lane == (bj & 63)) v[bj >> 6] = -INFINITY;
    if (lane == 0) op[r] = bj;
  }
}

// Fast path: 32-bit packed keys = monotone-f32(d) high 22 bits | (1023 - j).
// Keys globally unique (idx embedded). Downstream (max/mean over k) is
// order-independent, so only the SET of 20 must match the f64 reference.
// Wrong set requires a 22-bit key tie spanning the 20/21 boundary -> detected
// via (key20>>10)==(key21>>10) and re-run with the exact f64 path.
__device__ __forceinline__ void topk20(double (&v)[16], int lane, int* op) {
  unsigned s[16];
#pragma unroll
  for (int m = 0; m < 16; ++m) {
    float f = (float)v[m];
    unsigned u = __float_as_uint(f);
    u = (u & 0x80000000u) ? ~u : (u | 0x80000000u);
    s[m] = (u & ~1023u) | (unsigned)(1023 - (m * 64 + lane));
  }
  // Batcher odd-even mergesort, descending, fully unrolled (n=16)
#pragma unroll
  for (int p = 1; p < 16; p <<= 1) {
#pragma unroll
    for (int k = p; k >= 1; k >>= 1) {
#pragma unroll
      for (int j = k % p; j + k < 16; j += 2 * k) {
#pragma unroll
        for (int i = 0; i < k; ++i) {
          int a = j + i, b = j + i + k;
          if (b < 16 && (a / (2 * p)) == (b / (2 * p))) {
            unsigned hi = s[a] > s[b] ? s[a] : s[b];
            unsigned lo = s[a] > s[b] ? s[b] : s[a];
            s[a] = hi;
            s[b] = lo;
          }
        }
      }
    }
  }
  unsigned prev = 0;
#pragma unroll
  for (int r = 0; r < KNN; ++r) {
    unsigned win = s[0];
#pragma unroll
    for (int off = 32; off > 0; off >>= 1) {
      unsigned o = __shfl_xor(win, off, 64);
      win = o > win ? o : win;
    }
    if (lane == 0) op[r] = 1023 - (int)(win & 1023u);
    if (s[0] == win) {
#pragma unroll
      for (int i = 0; i < 15; ++i) s[i] = s[i + 1];
      s[15] = 0u;
    }
    prev = win;
  }
  unsigned win21 = s[0];
#pragma unroll
  for (int off = 32; off > 0; off >>= 1) {
    unsigned o = __shfl_xor(win21, off, 64);
    win21 = o > win21 ? o : win21;
  }
  if ((prev >> 10) == (win21 >> 10)) {  // boundary ambiguity (wave-uniform)
    topk_exact_f64(v, lane, op);
  }
}

// ---------------- transpose f32: (B,C,Np) -> (B,Np,C) ----------------
__global__ __launch_bounds__(256) void k_transpose(
    const float* __restrict__ in, float* __restrict__ out, int C, int Np) {
  int total = BB * C * Np;
  for (int t = blockIdx.x * 256 + threadIdx.x; t < total; t += gridDim.x * 256) {
    int c = t % C;
    int n = (t / C) % Np;
    int b = t / (C * Np);
    out[t] = in[((size_t)b * C + c) * Np + n];
  }
}

// ---------------- f32 -> bf16 convert ----------------
__global__ __launch_bounds__(256) void k_cvt_bf16(
    const float* __restrict__ in, __hip_bfloat16* __restrict__ out, int n) {
  int i = blockIdx.x * 256 + threadIdx.x;
  if (i < n) out[i] = __float2bfloat16(in[i]);
}

// ------- per-point squared norm (RECIP=0) or reciprocal norm (RECIP=1), f64 out -------
template <int RECIP>
__global__ __launch_bounds__(256) void k_rowsq(
    const float* __restrict__ A, int ld, int C, double* __restrict__ sq) {
  int p = blockIdx.x * 256 + threadIdx.x;
  if (p >= BB * NN) return;
  const float* row = A + (size_t)p * ld;
  double s = 0.0;
  for (int c = 0; c < C; ++c) { double v = (double)row[c]; s += v * v; }
  if (RECIP) {
    sq[p] = 1.0 / fmax(sqrt(s), 1e-12);
  } else {
    sq[p] = s;
  }
}

// ---- fused L1 knn (C=3): all points in LDS, f64 distances in-register, fast topk ----
__global__ __launch_bounds__(256) void k_knn3(
    const float* __restrict__ xs3, const double* __restrict__ sq, int* __restrict__ idx) {
  __shared__ float P[NN * 3];
  int b = blockIdx.x;
  const float* Xb = xs3 + (size_t)b * NN * 3;
  int tid = threadIdx.x;
  for (int t = tid; t < NN * 3; t += 256) P[t] = Xb[t];
  __syncthreads();
  int wave = tid >> 6, lane = tid & 63;
  int i = blockIdx.y * 4 + wave;
  double xi = (double)P[i * 3], yi = (double)P[i * 3 + 1], zi = (double)P[i * 3 + 2];
  double sqi = sq[b * NN + i];
  double v[16];
#pragma unroll
  for (int m = 0; m < 16; ++m) {
    int j = m * 64 + lane;
    double d = fma(xi, (double)P[j * 3], 0.0);
    d = fma(yi, (double)P[j * 3 + 1], d);
    d = fma(zi, (double)P[j * 3 + 2], d);
    v[m] = 2.0 * d - sqi - sq[b * NN + j];
  }
  int* op = idx + ((size_t)b * NN + i) * KNN;
  topk20(v, lane, op);
}

// ---- f64 gram: 128(i)x64(j) tiles, 8x4/thread, conflict-free strided-j, 1024 blocks ----
// MODE 1: D = 2*dot - sqA_i - sqB_j ; MODE 2: D = dot * rnA_i * rnB_j
template <int MODE>
__global__ __launch_bounds__(256) void k_gram2(
    const float* __restrict__ A, int lda, const float* __restrict__ Bm, int ldb,
    const double* __restrict__ sqA, const double* __restrict__ sqB,
    double* __restrict__ D, int C, int b0) {
  __shared__ double As[16][136];
  __shared__ double Bs[16][72];
  int bg = b0 + blockIdx.x;
  int bl = blockIdx.x;
  int j0 = blockIdx.y * 64;
  int i0 = blockIdx.z * 128;
  const float* Ab = A + (size_t)bg * NN * lda;
  const float* Bb = Bm + (size_t)bg * MM * ldb;
  int tx = threadIdx.x, ty = threadIdx.y;
  int tid = ty * 16 + tx;
  double acc[8][4] = {};
  for (int c0 = 0; c0 < C; c0 += 16) {
    for (int r = 0; r < 2; ++r) {
      int li = tid + r * 256;
      int row = li >> 2;
      int f = (li & 3) * 4;
      float4 av = *(const float4*)&Ab[(size_t)(i0 + row) * lda + c0 + f];
      As[f + 0][row] = (double)av.x;
      As[f + 1][row] = (double)av.y;
      As[f + 2][row] = (double)av.z;
      As[f + 3][row] = (double)av.w;
    }
    {
      int row = tid >> 2;
      int f = (tid & 3) * 4;
      float4 bv = *(const float4*)&Bb[(size_t)(j0 + row) * ldb + c0 + f];
      Bs[f + 0][row] = (double)bv.x;
      Bs[f + 1][row] = (double)bv.y;
      Bs[f + 2][row] = (double)bv.z;
      Bs[f + 3][row] = (double)bv.w;
    }
    __syncthreads();
#pragma unroll
    for (int k = 0; k < 16; ++k) {
      double a_[8], b_[4];
#pragma unroll
      for (int ii = 0; ii < 8; ++ii) a_[ii] = As[k][ty * 8 + ii];
#pragma unroll
      for (int jj = 0; jj < 4; ++jj) b_[jj] = Bs[k][jj * 16 + tx];
#pragma unroll
      for (int ii = 0; ii < 8; ++ii)
#pragma unroll
        for (int jj = 0; jj < 4; ++jj)
          acc[ii][jj] = fma(a_[ii], b_[jj], acc[ii][jj]);
    }
    __syncthreads();
  }
  for (int ii = 0; ii < 8; ++ii) {
    int i = i0 + ty * 8 + ii;
    for (int jj = 0; jj < 4; ++jj) {
      int j = j0 + jj * 16 + tx;
      double r = acc[ii][jj];
      if (MODE == 1) r = 2.0 * r - sqA[bg * NN + i] - sqB[bg * NN + j];
      if (MODE == 2) r = r * sqA[bg * NN + i] * sqB[bg * NN + j];
      D[((size_t)bl * NN + i) * MM + j] = r;
    }
  }
}

// ------- symmetric euclidean gram (A==B): triangular blocks, strided-j mapping -------
__global__ __launch_bounds__(256) void k_gram_sym(
    const float* __restrict__ A, int lda, const double* __restrict__ sqA,
    double* __restrict__ D, int C, int b0) {
  __shared__ double As[16][68];
  __shared__ double Bs[16][68];
  __shared__ double T[64][65];
  int p = blockIdx.y;  // 0..135 triangular pair index
  int r = (int)((sqrtf(8.f * p + 1.f) - 1.f) * 0.5f);
  while ((r + 1) * (r + 2) / 2 <= p) ++r;
  while (r * (r + 1) / 2 > p) --r;
  int cc = p - r * (r + 1) / 2;
  int i0 = r * 64, j0 = cc * 64;
  int bg = b0 + blockIdx.x;
  int bl = blockIdx.x;
  const float* Ab = A + (size_t)bg * NN * lda;
  int tx = threadIdx.x, ty = threadIdx.y;
  int tid = ty * 16 + tx;
  double acc[4][4] = {};
  for (int c0 = 0; c0 < C; c0 += 16) {
    for (int rr = 0; rr < 4; ++rr) {
      int li = tid + rr * 256;
      int row = li >> 4, k = li & 15;
      int c = c0 + k;
      As[k][row] = (c < C) ? (double)Ab[(size_t)(i0 + row) * lda + c] : 0.0;
      Bs[k][row] = (c < C) ? (double)Ab[(size_t)(j0 + row) * lda + c] : 0.0;
    }
    __syncthreads();
#pragma unroll
    for (int k = 0; k < 16; ++k) {
      double a_[4], b_[4];
#pragma unroll
      for (int ii = 0; ii < 4; ++ii) a_[ii] = As[k][ty * 4 + ii];
#pragma unroll
      for (int jj = 0; jj < 4; ++jj) b_[jj] = Bs[k][jj * 16 + tx];
#pragma unroll
      for (int ii = 0; ii < 4; ++ii)
#pragma unroll
        for (int jj = 0; jj < 4; ++jj)
          acc[ii][jj] = fma(a_[ii], b_[jj], acc[ii][jj]);
    }
    __syncthreads();
  }
  for (int ii = 0; ii < 4; ++ii) {
    int i = i0 + ty * 4 + ii;
    for (int jj = 0; jj < 4; ++jj) {
      int j = j0 + jj * 16 + tx;
      double v = 2.0 * acc[ii][jj] - sqA[bg * NN + i] - sqA[bg * NN + j];
      D[((size_t)bl * NN + i) * MM + j] = v;
      T[jj * 16 + tx][ty * 4 + ii] = v;
    }
  }
  if (i0 != j0) {
    __syncthreads();
    for (int rr = 0; rr < 16; ++rr) {
      int li = tid + rr * 256;
      int jrow = li >> 6, il = li & 63;
      D[((size_t)bl * NN + j0 + jrow) * MM + i0 + il] = T[jrow][il];
    }
  }
}

// ------- top-20 per row via fast screened selection; grid (batch, rowblock) -------
__global__ __launch_bounds__(256) void k_topk(const double* __restrict__ D,
                                              int* __restrict__ idx, int b0) {
  int wave = threadIdx.x >> 6;
  int lane = threadIdx.x & 63;
  int bl = blockIdx.x;
  int row = blockIdx.y * 4 + wave;
  const double* rp = D + ((size_t)bl * NN + row) * MM;
  double v[16];
#pragma unroll
  for (int m = 0; m < 16; ++m) v[m] = rp[m * 64 + lane];
  int* op = idx + ((size_t)(b0 + bl) * NN + row) * KNN;
  topk20(v, lane, op);
}

// ------- per-point feature matmul (64x64 tile): batch = blockIdx.x (XCD affinity) -------
// mode 0: weff = w[o,c]; mode 1: weff = w[o,C+c] - w[o,c]
__global__ __launch_bounds__(256) void k_featmm(
    const float* __restrict__ src, int lds_, const float* __restrict__ w, int CW,
    float* __restrict__ out, int C, int O, int mode, int Np) {
  __shared__ float As[16][68];
  __shared__ float Ws[16][68];
  int b = blockIdx.x;
  int o0 = blockIdx.y * 64;
  int j0 = blockIdx.z * 64;
  int tx = threadIdx.x, ty = threadIdx.y;
  int tid = ty * 16 + tx;
  const float* Sb = src + (size_t)b * Np * lds_;
  float acc[4][4] = {};
  for (int c0 = 0; c0 < C; c0 += 16) {
    for (int r = 0; r < 4; ++r) {
      int li = tid + r * 256;
      int row = li >> 4, k = li & 15;
      int c = c0 + k;
      As[k][row] = (c < C) ? Sb[(size_t)(j0 + row) * lds_ + c] : 0.f;
      float wv = 0.f;
      if (c < C) {
        const float* wr = w + (size_t)(o0 + row) * CW;
        wv = mode == 0 ? wr[c] : (wr[C + c] - wr[c]);
      }
      Ws[k][row] = wv;
    }
    __syncthreads();
#pragma unroll
    for (int k = 0; k < 16; ++k) {
      float a_[4], b_[4];
#pragma unroll
      for (int ii = 0; ii < 4; ++ii) a_[ii] = As[k][ty * 4 + ii];
#pragma unroll
      for (int jj = 0; jj < 4; ++jj) b_[jj] = Ws[k][tx * 4 + jj];
#pragma unroll
      for (int ii = 0; ii < 4; ++ii)
#pragma unroll
        for (int jj = 0; jj < 4; ++jj)
          acc[ii][jj] = fmaf(a_[ii], b_[jj], acc[ii][jj]);
    }
    __syncthreads();
  }
  for (int ii = 0; ii < 4; ++ii) {
    int j = j0 + ty * 4 + ii;
    float4 v;
    float* vp = &v.x;
    for (int jj = 0; jj < 4; ++jj) vp[jj] = acc[ii][jj];
    *(float4*)&out[((size_t)b * Np + j) * O + o0 + tx * 4] = v;
  }
}

// ---- layer-5 GEMM via bf16 MFMA: per-wave 16x16 tile, frags direct from global ----
__global__ __launch_bounds__(256) void k_gemm5_mfma(
    const __hip_bfloat16* __restrict__ cath, const __hip_bfloat16* __restrict__ w5h,
    float* __restrict__ out) {
  int b = blockIdx.x;
  int j0 = blockIdx.y * 16;
  int o0 = blockIdx.z * 64 + (threadIdx.x >> 6) * 16;
  int lane = threadIdx.x & 63;
  int m = lane & 15;
  int quad = lane >> 4;
  const __hip_bfloat16* arow = cath + ((size_t)b * NN + j0 + m) * 512 + quad * 8;
  const __hip_bfloat16* brow = w5h + (size_t)(o0 + m) * 512 + quad * 8;
  f32x4 acc = {0.f, 0.f, 0.f, 0.f};
#pragma unroll
  for (int c0 = 0; c0 < 512; c0 += 32) {
    bf16x8 a = *(const bf16x8*)(arow + c0);
    bf16x8 bb = *(const bf16x8*)(brow + c0);
    acc = __builtin_amdgcn_mfma_f32_16x16x32_bf16(a, bb, acc, 0, 0, 0);
  }
  float* obase = &out[((size_t)b * NN + j0 + quad * 4) * 512 + o0 + m];
#pragma unroll
  for (int r = 0; r < 4; ++r) obase[(size_t)r * 512] = acc[r];
}

// ------- fused gather: per (n,o) compute max_k y, accumulate BN stats; b = blockIdx.x -------
__global__ __launch_bounds__(256) void k_gather(
    const float* __restrict__ u, const float* __restrict__ t, const int* __restrict__ idx,
    double* __restrict__ stats, float* __restrict__ mx, int O, int srcNp) {
  __shared__ int lidx[16 * KNN];
  __shared__ double rs[256];
  __shared__ double rq[256];
  int b = blockIdx.x;
  int n0 = blockIdx.y * 16;
  int o0 = blockIdx.z * 64;
  int tid = threadIdx.x;
  int lane = tid & 63, nsl = tid >> 6;
  for (int w = tid; w < 16 * KNN; w += 256)
    lidx[w] = idx[((size_t)b * NN + n0) * KNN + w];
  __syncthreads();
  int oo = o0 + lane;
  double s1 = 0.0, s2 = 0.0;
  for (int ns = nsl; ns < 16; ns += 4) {
    size_t row = (size_t)b * NN + n0 + ns;
    float tv = t[row * O + oo];
    float mxv = -INFINITY, a1 = 0.f, a2 = 0.f;
#pragma unroll
    for (int k = 0; k < KNN; ++k) {
      int j = lidx[ns * KNN + k];
      float yv = u[((size_t)b * srcNp + j) * O + oo] + tv;
      mxv = fmaxf(mxv, yv);
      a1 += yv;
      a2 = fmaf(yv, yv, a2);
    }
    mx[row * O + oo] = mxv;
    s1 += (double)a1;
    s2 += (double)a2;
  }
  rs[tid] = s1;
  rq[tid] = s2;
  __syncthreads();
  if (tid < 64) {
    s1 = rs[tid] + rs[tid + 64] + rs[tid + 128] + rs[tid + 192];
    s2 = rq[tid] + rq[tid + 64] + rq[tid + 128] + rq[tid + 192];
    atomicAdd(&stats[o0 + tid], s1);
    atomicAdd(&stats[O + o0 + tid], s2);
  }
}

// ---------------- fold BN into per-channel scale/shift ----------------
__global__ void k_bnfin(const double* __restrict__ stats, const float* __restrict__ gamma,
                        const float* __restrict__ beta, float* __restrict__ sc,
                        int O, double cnt) {
  int o = threadIdx.x;
  if (o >= O) return;
  double mean = stats[o] / cnt;
  double var = stats[O + o] / cnt - mean * mean;
  if (var < 0.0) var = 0.0;
  double rstd = 1.0 / sqrt(var + 1e-5);
  float s = gamma[o] * (float)rstd;
  float c = beta[o] - (float)mean * s;
  sc[o] = s;
  sc[O + o] = c;
}

// --- apply BN+lrelu to stored max, write cat slice (f32 + bf16 mirror for L5 MFMA) ---
__global__ __launch_bounds__(256) void k_bnapply(
    const float* __restrict__ mx, const float* __restrict__ u, const float* __restrict__ t,
    const int* __restrict__ idx, const float* __restrict__ sc, float* __restrict__ cat,
    __hip_bfloat16* __restrict__ cath, int coff, int O, int srcNp) {
  int i = blockIdx.x * 256 + threadIdx.x;
  int total = BB * NN * O;
  if (i >= total) return;
  int oo = i % O;
  int n = (i / O) % NN;
  int b = i / (O * NN);
  float s = sc[oo], c = sc[O + oo];
  float v;
  if (s >= 0.f) {
    v = mx[i];
  } else {  // monotone-decreasing transform needs min_k y (never hit with gamma=1)
    float tv = t[i];
    float mn = INFINITY;
    for (int k = 0; k < KNN; ++k) {
      int j = idx[((size_t)b * NN + n) * KNN + k];
      mn = fminf(mn, u[((size_t)b * srcNp + j) * O + oo] + tv);
    }
    v = mn;
  }
  float a = s * v + c;
  a = (a >= 0.f) ? a : NEG_SLOPE * a;
  size_t oidx = ((size_t)b * NN + n) * 512 + coff + oo;
  cat[oidx] = a;
  cath[oidx] = __float2bfloat16(a);
}

// ------- layer 5 streaming stats over stored y5 (B,N,512) -------
__global__ __launch_bounds__(256) void k_stats512(
    const float* __restrict__ y5, double* __restrict__ stats) {
  int b = blockIdx.y;
  int n0 = blockIdx.x * 32;
  int tid = threadIdx.x;
  for (int part = 0; part < 2; ++part) {
    int oo = tid + part * 256;
    float a1 = 0.f, a2 = 0.f;
    for (int ns = 0; ns < 32; ++ns) {
      float v = y5[((size_t)b * NN + n0 + ns) * 512 + oo];
      a1 += v;
      a2 = fmaf(v, v, a2);
    }
    atomicAdd(&stats[oo], (double)a1);
    atomicAdd(&stats[512 + oo], (double)a2);
  }
}

// ------- layer 5 streaming finalize: BN+lrelu on stored y5, transpose, f32 store -------
__global__ __launch_bounds__(256) void k_final5b(
    const float* __restrict__ y5, const float* __restrict__ sc, float* __restrict__ out) {
  __shared__ float tile[64][65];
  int b = blockIdx.z;
  int n0 = blockIdx.x * 64;
  int o0 = blockIdx.y * 64;
  int tid = threadIdx.x;
  for (int r = 0; r < 16; ++r) {
    int li = tid + r * 256;
    int nl = li >> 6, ol = li & 63;
    float v = y5[((size_t)b * NN + n0 + nl) * 512 + o0 + ol];
    float a = sc[o0 + ol] * v + sc[512 + o0 + ol];
    a = (a >= 0.f) ? a : NEG_SLOPE * a;
    tile[nl][ol] = a;
  }
  __syncthreads();
  for (int r = 0; r < 16; ++r) {
    int li = tid + r * 256;
    int ol = li >> 6, nl = li & 63;
    out[((size_t)b * 512 + o0 + ol) * NN + n0 + nl] = tile[nl][ol];
  }
}

// ------- fallback layer 5 (CB<2): GEMM+stats recompute pass -------
__global__ __launch_bounds__(256) void k_mmstats(
    const float* __restrict__ src, const float* __restrict__ w,
    double* __restrict__ stats) {
  __shared__ float As[16][68];
  __shared__ float Ws[16][68];
  __shared__ float redS[16][64];
  __shared__ float redQ[16][64];
  int b = blockIdx.z;
  int j0 = blockIdx.y * 64;
  int o0 = blockIdx.x * 64;
  int tx = threadIdx.x, ty = threadIdx.y;
  int tid = ty * 16 + tx;
  const float* Sb = src + (size_t)b * NN * 512;
  float acc[4][4] = {};
  for (int c0 = 0; c0 < 512; c0 += 16) {
    for (int r = 0; r < 4; ++r) {
      int li = tid + r * 256;
      int row = li >> 4, k = li & 15;
      As[k][row] = Sb[(size_t)(j0 + row) * 512 + c0 + k];
      Ws[k][row] = w[(size_t)(o0 + row) * 512 + c0 + k];
    }
    __syncthreads();
#pragma unroll
    for (int k = 0; k < 16; ++k) {
      float a_[4], b_[4];
#pragma unroll
      for (int ii = 0; ii < 4; ++ii) a_[ii] = As[k][ty * 4 + ii];
#pragma unroll
      for (int jj = 0; jj < 4; ++jj) b_[jj] = Ws[k][tx * 4 + jj];
#pragma unroll
      for (int ii = 0; ii < 4; ++ii)
#pragma unroll
        for (int jj = 0; jj < 4; ++jj)
          acc[ii][jj] = fmaf(a_[ii], b_[jj], acc[ii][jj]);
    }
    __syncthreads();
  }
  for (int jj = 0; jj < 4; ++jj) {
    float s = 0.f, q = 0.f;
    for (int ii = 0; ii < 4; ++ii) { float v = acc[ii][jj]; s += v; q += v * v; }
    redS[ty][tx * 4 + jj] = s;
    redQ[ty][tx * 4 + jj] = q;
  }
  __syncthreads();
  if (tid < 64) {
    float s = 0.f, q = 0.f;
    for (int r = 0; r < 16; ++r) { s += redS[r][tid]; q += redQ[r][tid]; }
    atomicAdd(&stats[o0 + tid], (double)s);
    atomicAdd(&stats[512 + o0 + tid], (double)q);
  }
}

// ------- fallback layer 5 (CB<2): recompute GEMM, BN+lrelu, transposed store -------
__global__ __launch_bounds__(256) void k_final5(
    const float* __restrict__ src, const float* __restrict__ w,
    const float* __restrict__ sc, float* __restrict__ out) {
  __shared__ float As[16][68];
  __shared__ float Ws[16][68];
  __shared__ float tile[64][65];
  int b = blockIdx.z;
  int j0 = blockIdx.y * 64;
  int o0 = blockIdx.x * 64;
  int tx = threadIdx.x, ty = threadIdx.y;
  int tid = ty * 16 + tx;
  const float* Sb = src + (size_t)b * NN * 512;
  float acc[4][4] = {};
  for (int c0 = 0; c0 < 512; c0 += 16) {
    for (int r = 0; r < 4; ++r) {
      int li = tid + r * 256;
      int row = li >> 4, k = li & 15;
      As[k][row] = Sb[(size_t)(j0 + row) * 512 + c0 + k];
      Ws[k][row] = w[(size_t)(o0 + row) * 512 + c0 + k];
    }
    __syncthreads();
#pragma unroll
    for (int k = 0; k < 16; ++k) {
      float a_[4], b_[4];
#pragma unroll
      for (int ii = 0; ii < 4; ++ii) a_[ii] = As[k][ty * 4 + ii];
#pragma unroll
      for (int jj = 0; jj < 4; ++jj) b_[jj] = Ws[k][tx * 4 + jj];
#pragma unroll
      for (int ii = 0; ii < 4; ++ii)
#pragma unroll
        for (int jj = 0; jj < 4; ++jj)
          acc[ii][jj] = fmaf(a_[ii], b_[jj], acc[ii][jj]);
    }
    __syncthreads();
  }
  for (int ii = 0; ii < 4; ++ii)
    for (int jj = 0; jj < 4; ++jj) {
      int nl = ty * 4 + ii, ol = tx * 4 + jj;
      float a = sc[o0 + ol] * acc[ii][jj] + sc[512 + o0 + ol];
      a = (a >= 0.f) ? a : NEG_SLOPE * a;
      tile[nl][ol] = a;
    }
  __syncthreads();
  for (int r = 0; r < 16; ++r) {
    int li = tid + r * 256;
    int ol = li >> 6, nl = li & 63;
    out[((size_t)b * 512 + o0 + ol) * NN + j0 + nl] = tile[nl][ol];
  }
}

// =====================================================================================
// r12: fast set-exact top-20 (32-bit packed keys: monotone-f32 high 22 bits + inverted
// idx low 10; Batcher lane-sort + shfl-max rounds; f64 fallback on detected boundary
// key-tie). Downstream max/mean over k is order-independent -> only the SET must match.
// Applied to k_topk (3 layers) and k_knn3. Rest unchanged from r11.
extern "C" void kernel_launch(void* const* d_in, const int* in_sizes, int n_in,
                              void* d_out, int out_size, void* d_ws, size_t ws_size,
                              hipStream_t stream) {
  const float* x = (const float*)d_in[0];
  const float* y = (const float*)d_in[1];
  const float* w1 = (const float*)d_in[2];
  const float* w2 = (const float*)d_in[3];
  const float* w3 = (const float*)d_in[4];
  const float* w4 = (const float*)d_in[5];
  const float* w5 = (const float*)d_in[6];
  const float* g1 = (const float*)d_in[7];
  const float* b1 = (const float*)d_in[8];
  const float* g2 = (const float*)d_in[9];
  const float* b2 = (const float*)d_in[10];
  const float* g3 = (const float*)d_in[11];
  const float* b3 = (const float*)d_in[12];
  const float* g4 = (const float*)d_in[13];
  const float* b4 = (const float*)d_in[14];
  const float* g5 = (const float*)d_in[15];
  const float* b5 = (const float*)d_in[16];

  char* base = (char*)d_ws;
  size_t off = 0;
  auto alloc = [&](size_t bytes) -> char* {
    char* p = base + off;
    off += (bytes + 255) & ~(size_t)255;
    return p;
  };
  double* st = (double*)alloc(1024 * 8);
  float* sc  = (float*)alloc(1024 * 4);
  double* sq  = (double*)alloc((size_t)BB * NN * 8);
  double* rnx = (double*)alloc((size_t)BB * NN * 8);
  double* rny = (double*)alloc((size_t)BB * MM * 8);
  int*   idxb = (int*)alloc((size_t)BB * NN * KNN * 4);
  float* xs3 = (float*)alloc((size_t)BB * NN * 3 * 4);
  float* ys  = (float*)alloc((size_t)BB * MM * 128 * 4);
  float* cat = (float*)alloc((size_t)BB * NN * 512 * 4);
  __hip_bfloat16* cath = (__hip_bfloat16*)alloc((size_t)BB * NN * 512 * 2);
  __hip_bfloat16* w5h  = (__hip_bfloat16*)alloc((size_t)512 * 512 * 2);
  size_t ddBatchBytes = (size_t)NN * MM * 8;  // 8 MB per batch (f64)
  size_t avail = (ws_size > off) ? (ws_size - off) : 0;
  int CB = (int)(avail / ddBatchBytes);
  if (CB < 1) CB = 1;
  if (CB > BB) CB = BB;
  char*  U   = alloc((size_t)CB * ddBatchBytes);
  double* DD = (double*)U;                     // dist/simi chunk (f64), dead after topk
  float* tt  = (float*)U;                      // center term (f32, <=8MB), after DD dead
  float* y5  = (float*)U;                      // layer-5 pre-BN (16MB, needs CB>=2)
  float* uu  = (float*)d_out;                  // source term (<=8MB)
  float* mx  = (float*)d_out + (size_t)2 * 1024 * 1024;  // max_k y (<=8MB)
  float* outp = (float*)d_out;

  const dim3 blk2(16, 16);
  const double cntE = (double)BB * NN * KNN;

  // knn: sym=1 -> triangular symmetric euclid gram (A==B); else general 128x64 MODE
  auto knn = [&](const float* A, int lda, const float* Bm, int ldb,
                 const double* sa, const double* sb, int C, int mode, int sym) {
    for (int b0 = 0; b0 < BB; b0 += CB) {
      int cb = (BB - b0 < CB) ? (BB - b0) : CB;
      if (sym) {
        k_gram_sym<<<dim3(cb, 136), blk2, 0, stream>>>(A, lda, sa, DD, C, b0);
      } else {
        dim3 g(cb, MM / 64, NN / 128);
        if (mode == 1) k_gram2<1><<<g, blk2, 0, stream>>>(A, lda, Bm, ldb, sa, sb, DD, C, b0);
        else           k_gram2<2><<<g, blk2, 0, stream>>>(A, lda, Bm, ldb, sa, sb, DD, C, b0);
      }
      k_topk<<<dim3(cb, 256), 256, 0, stream>>>(DD, idxb, b0);
    }
  };

  auto edge_layer = [&](const float* ctr, int ldc, const float* src, int ldsrc, int srcNp,
                        const float* w, int CW, const float* g, const float* bb,
                        int C, int O, int coff) {
    k_featmm<<<dim3(8, O / 64, 16), blk2, 0, stream>>>(src, ldsrc, w, CW, uu, C, O, 0, srcNp);
    k_featmm<<<dim3(8, O / 64, 16), blk2, 0, stream>>>(ctr, ldc, w, CW, tt, C, O, 1, NN);
    hipMemsetAsync(st, 0, 1024 * 8, stream);
    k_gather<<<dim3(BB, NN / 16, O / 64), 256, 0, stream>>>(uu, tt, idxb, st, mx, O, srcNp);
    k_bnfin<<<1, O, 0, stream>>>(st, g, bb, sc, O, cntE);
    k_bnapply<<<(BB * NN * O + 255) / 256, 256, 0, stream>>>(mx, uu, tt, idxb, sc, cat,
                                                             cath, coff, O, srcNp);
  };

  // ---- input transposes + w5 bf16 convert ----
  k_transpose<<<96, 256, 0, stream>>>(x, xs3, 3, NN);
  k_transpose<<<2048, 256, 0, stream>>>(y, ys, 128, MM);
  k_cvt_bf16<<<1024, 256, 0, stream>>>(w5, w5h, 512 * 512);

  // ---- layer 1: C=3, O=64 (fused knn, no DD) ----
  k_rowsq<0><<<32, 256, 0, stream>>>(xs3, 3, 3, sq);
  k_knn3<<<dim3(BB, 256), 256, 0, stream>>>(xs3, sq, idxb);
  edge_layer(xs3, 3, xs3, 3, NN, w1, 6, g1, b1, 3, 64, 0);

  // ---- layer 2: x1 = cat[:,0:64], C=64, O=64 ----
  k_rowsq<0><<<32, 256, 0, stream>>>(cat, 512, 64, sq);
  knn(cat, 512, cat, 512, sq, sq, 64, 1, 1);
  edge_layer(cat, 512, cat, 512, NN, w2, 128, g2, b2, 64, 64, 64);

  // ---- layer 3: x2 = cat[:,64:128], C=64, O=128 ----
  k_rowsq<0><<<32, 256, 0, stream>>>(cat + 64, 512, 64, sq);
  knn(cat + 64, 512, cat + 64, 512, sq, sq, 64, 1, 1);
  edge_layer(cat + 64, 512, cat + 64, 512, NN, w3, 128, g3, b3, 64, 128, 128);

  // ---- layer 4 (IA): x3 = cat[:,128:256], src = y (cosine knn), C=128, O=256 ----
  k_rowsq<1><<<32, 256, 0, stream>>>(cat + 128, 512, 128, rnx);
  k_rowsq<1><<<32, 256, 0, stream>>>(ys, 128, 128, rny);
  knn(cat + 128, 512, ys, 128, rnx, rny, 128, 2, 0);
  edge_layer(cat + 128, 512, ys, 128, MM, w4, 256, g4, b4, 128, 256, 256);

  // ---- layer 5: bf16-MFMA GEMM -> y5, BN over (B,N), lrelu, transposed out ----
  hipMemsetAsync(st, 0, 1024 * 8, stream);
  if (CB >= 2) {
    k_gemm5_mfma<<<dim3(BB, 64, 8), 256, 0, stream>>>(cath, w5h, y5);
    k_stats512<<<dim3(32, 8), 256, 0, stream>>>(y5, st);
    k_bnfin<<<1, 512, 0, stream>>>(st, g5, b5, sc, 512, (double)(BB * NN));
    k_final5b<<<dim3(16, 8, 8), 256, 0, stream>>>(y5, sc, outp);
  } else {
    k_mmstats<<<dim3(8, 16, 8), blk2, 0, stream>>>(cat, w5, st);
    k_bnfin<<<1, 512, 0, stream>>>(st, g5, b5, sc, 512, (double)(BB * NN));
    k_final5<<<dim3(8, 16, 8), blk2, 0, stream>>>(cat, w5, sc, outp);
  }
}

// Round 13
// 675.971 us; speedup vs baseline: 1.1518x; 1.0280x over previous
//
#include <hip/hip_runtime.h>
#include <hip/hip_bf16.h>

#define KNN 20
#define NEG_SLOPE 0.2f

constexpr int BB = 8;
constexpr int NN = 1024;
constexpr int MM = 1024;

typedef short bf16x8 __attribute__((ext_vector_type(8)));
typedef float f32x4 __attribute__((ext_vector_type(4)));

// ================= top-20 selection (set-exact) =================
__device__ __forceinline__ unsigned pack_key(double d, int j) {
  float f = (float)d;
  unsigned u = __float_as_uint(f);
  u = (u & 0x80000000u) ? ~u : (u | 0x80000000u);
  return (u & ~1023u) | (unsigned)(1023 - j);
}

// Exact f64 reference path (jax tie semantics: larger value, tie -> lower idx).
__device__ __forceinline__ void topk_exact_f64(double (&v)[16], int lane, int* op) {
  for (int r = 0; r < KNN; ++r) {
    double bv = -INFINITY;
    int bj = MM;
#pragma unroll
    for (int m = 0; m < 16; ++m) {
      if (v[m] > bv) { bv = v[m]; bj = m * 64 + lane; }
    }
#pragma unroll
    for (int off = 32; off > 0; off >>= 1) {
      double ov = __shfl_xor(bv, off, 64);
      int oj = __shfl_xor(bj, off, 64);
      if (ov > bv || (ov == bv && oj < bj)) { bv = ov; bj = oj; }
    }
    if (bj < MM && lane == (bj & 63)) v[bj >> 6] = -INFINITY;
    if (lane == 0) op[r] = bj;
  }
}

// Fast path on 32-bit packed keys (22-bit monotone-f32 | inverted idx).
// Returns true if the 20/21 boundary is ambiguous at 22-bit granularity.
__device__ __forceinline__ bool topk20_fast(unsigned (&s)[16], int lane, int* op) {
  // Batcher odd-even mergesort, descending, fully unrolled (n=16)
#pragma unroll
  for (int p = 1; p < 16; p <<= 1) {
#pragma unroll
    for (int k = p; k >= 1; k >>= 1) {
#pragma unroll
      for (int j = k % p; j + k < 16; j += 2 * k) {
#pragma unroll
        for (int i = 0; i < k; ++i) {
          int a = j + i, b = j + i + k;
          if (b < 16 && (a / (2 * p)) == (b / (2 * p))) {
            unsigned hi = s[a] > s[b] ? s[a] : s[b];
            unsigned lo = s[a] > s[b] ? s[b] : s[a];
            s[a] = hi;
            s[b] = lo;
          }
        }
      }
    }
  }
  unsigned prev = 0;
#pragma unroll
  for (int r = 0; r < KNN; ++r) {
    unsigned win = s[0];
#pragma unroll
    for (int off = 32; off > 0; off >>= 1) {
      unsigned o = __shfl_xor(win, off, 64);
      win = o > win ? o : win;
    }
    if (lane == 0) op[r] = 1023 - (int)(win & 1023u);
    if (s[0] == win) {
#pragma unroll
      for (int i = 0; i < 15; ++i) s[i] = s[i + 1];
      s[15] = 0u;
    }
    prev = win;
  }
  unsigned win21 = s[0];
#pragma unroll
  for (int off = 32; off > 0; off >>= 1) {
    unsigned o = __shfl_xor(win21, off, 64);
    win21 = o > win21 ? o : win21;
  }
  return (prev >> 10) == (win21 >> 10);
}

// ---------------- transpose f32: (B,C,Np) -> (B,Np,C) ----------------
__global__ __launch_bounds__(256) void k_transpose(
    const float* __restrict__ in, float* __restrict__ out, int C, int Np) {
  int total = BB * C * Np;
  for (int t = blockIdx.x * 256 + threadIdx.x; t < total; t += gridDim.x * 256) {
    int c = t % C;
    int n = (t / C) % Np;
    int b = t / (C * Np);
    out[t] = in[((size_t)b * C + c) * Np + n];
  }
}

// ---------------- f32 -> bf16 convert ----------------
__global__ __launch_bounds__(256) void k_cvt_bf16(
    const float* __restrict__ in, __hip_bfloat16* __restrict__ out, int n) {
  int i = blockIdx.x * 256 + threadIdx.x;
  if (i < n) out[i] = __float2bfloat16(in[i]);
}

// ------- per-point squared norm (RECIP=0) or reciprocal norm (RECIP=1), f64 out -------
template <int RECIP>
__global__ __launch_bounds__(256) void k_rowsq(
    const float* __restrict__ A, int ld, int C, double* __restrict__ sq) {
  int p = blockIdx.x * 256 + threadIdx.x;
  if (p >= BB * NN) return;
  const float* row = A + (size_t)p * ld;
  double s = 0.0;
  for (int c = 0; c < C; ++c) { double v = (double)row[c]; s += v * v; }
  if (RECIP) {
    sq[p] = 1.0 / fmax(sqrt(s), 1e-12);
  } else {
    sq[p] = s;
  }
}

// ---- fused L1 knn (C=3): all points in LDS, f64 distances in-register, fast topk ----
__global__ __launch_bounds__(256) void k_knn3(
    const float* __restrict__ xs3, const double* __restrict__ sq, int* __restrict__ idx) {
  __shared__ float P[NN * 3];
  int b = blockIdx.x;
  const float* Xb = xs3 + (size_t)b * NN * 3;
  int tid = threadIdx.x;
  for (int t = tid; t < NN * 3; t += 256) P[t] = Xb[t];
  __syncthreads();
  int wave = tid >> 6, lane = tid & 63;
  int i = blockIdx.y * 4 + wave;
  double xi = (double)P[i * 3], yi = (double)P[i * 3 + 1], zi = (double)P[i * 3 + 2];
  double sqi = sq[b * NN + i];
  double v[16];
  unsigned s[16];
#pragma unroll
  for (int m = 0; m < 16; ++m) {
    int j = m * 64 + lane;
    double d = fma(xi, (double)P[j * 3], 0.0);
    d = fma(yi, (double)P[j * 3 + 1], d);
    d = fma(zi, (double)P[j * 3 + 2], d);
    v[m] = 2.0 * d - sqi - sq[b * NN + j];
    s[m] = pack_key(v[m], j);
  }
  int* op = idx + ((size_t)b * NN + i) * KNN;
  if (topk20_fast(s, lane, op)) topk_exact_f64(v, lane, op);
}

// ---- f64 gram: 128(i)x64(j) tiles, 8x4/thread; writes DD f64 + packed keys ----
// MODE 1: D = 2*dot - sqA_i - sqB_j ; MODE 2: D = dot * rnA_i * rnB_j
// LDS pads 137/73: staging-write banks spread {0,8,16,24} (was 4-way at 136/72).
template <int MODE>
__global__ __launch_bounds__(256) void k_gram2(
    const float* __restrict__ A, int lda, const float* __restrict__ Bm, int ldb,
    const double* __restrict__ sqA, const double* __restrict__ sqB,
    double* __restrict__ D, unsigned* __restrict__ kk, int C, int b0) {
  __shared__ double As[16][137];
  __shared__ double Bs[16][73];
  int bg = b0 + blockIdx.x;
  int bl = blockIdx.x;
  int j0 = blockIdx.y * 64;
  int i0 = blockIdx.z * 128;
  const float* Ab = A + (size_t)bg * NN * lda;
  const float* Bb = Bm + (size_t)bg * MM * ldb;
  int tx = threadIdx.x, ty = threadIdx.y;
  int tid = ty * 16 + tx;
  double acc[8][4] = {};
  for (int c0 = 0; c0 < C; c0 += 16) {
    for (int r = 0; r < 2; ++r) {
      int li = tid + r * 256;
      int row = li >> 2;
      int f = (li & 3) * 4;
      float4 av = *(const float4*)&Ab[(size_t)(i0 + row) * lda + c0 + f];
      As[f + 0][row] = (double)av.x;
      As[f + 1][row] = (double)av.y;
      As[f + 2][row] = (double)av.z;
      As[f + 3][row] = (double)av.w;
    }
    {
      int row = tid >> 2;
      int f = (tid & 3) * 4;
      float4 bv = *(const float4*)&Bb[(size_t)(j0 + row) * ldb + c0 + f];
      Bs[f + 0][row] = (double)bv.x;
      Bs[f + 1][row] = (double)bv.y;
      Bs[f + 2][row] = (double)bv.z;
      Bs[f + 3][row] = (double)bv.w;
    }
    __syncthreads();
#pragma unroll
    for (int k = 0; k < 16; ++k) {
      double a_[8], b_[4];
#pragma unroll
      for (int ii = 0; ii < 8; ++ii) a_[ii] = As[k][ty * 8 + ii];
#pragma unroll
      for (int jj = 0; jj < 4; ++jj) b_[jj] = Bs[k][jj * 16 + tx];
#pragma unroll
      for (int ii = 0; ii < 8; ++ii)
#pragma unroll
        for (int jj = 0; jj < 4; ++jj)
          acc[ii][jj] = fma(a_[ii], b_[jj], acc[ii][jj]);
    }
    __syncthreads();
  }
  for (int ii = 0; ii < 8; ++ii) {
    int i = i0 + ty * 8 + ii;
    for (int jj = 0; jj < 4; ++jj) {
      int j = j0 + jj * 16 + tx;
      double r = acc[ii][jj];
      if (MODE == 1) r = 2.0 * r - sqA[bg * NN + i] - sqB[bg * NN + j];
      if (MODE == 2) r = r * sqA[bg * NN + i] * sqB[bg * NN + j];
      size_t o = ((size_t)bl * NN + i) * MM + j;
      D[o] = r;
      kk[o] = pack_key(r, j);
    }
  }
}

// ------- symmetric euclidean gram (A==B): triangular blocks; DD + keys (+mirror) -------
__global__ __launch_bounds__(256) void k_gram_sym(
    const float* __restrict__ A, int lda, const double* __restrict__ sqA,
    double* __restrict__ D, unsigned* __restrict__ kk, int C, int b0) {
  __shared__ double As[16][69];
  __shared__ double Bs[16][69];
  __shared__ double T[64][65];
  int p = blockIdx.y;  // 0..135 triangular pair index
  int r = (int)((sqrtf(8.f * p + 1.f) - 1.f) * 0.5f);
  while ((r + 1) * (r + 2) / 2 <= p) ++r;
  while (r * (r + 1) / 2 > p) --r;
  int cc = p - r * (r + 1) / 2;
  int i0 = r * 64, j0 = cc * 64;
  int bg = b0 + blockIdx.x;
  int bl = blockIdx.x;
  const float* Ab = A + (size_t)bg * NN * lda;
  int tx = threadIdx.x, ty = threadIdx.y;
  int tid = ty * 16 + tx;
  double acc[4][4] = {};
  for (int c0 = 0; c0 < C; c0 += 16) {
    for (int rr = 0; rr < 4; ++rr) {
      int li = tid + rr * 256;
      int row = li >> 4, k = li & 15;
      int c = c0 + k;
      As[k][row] = (c < C) ? (double)Ab[(size_t)(i0 + row) * lda + c] : 0.0;
      Bs[k][row] = (c < C) ? (double)Ab[(size_t)(j0 + row) * lda + c] : 0.0;
    }
    __syncthreads();
#pragma unroll
    for (int k = 0; k < 16; ++k) {
      double a_[4], b_[4];
#pragma unroll
      for (int ii = 0; ii < 4; ++ii) a_[ii] = As[k][ty * 4 + ii];
#pragma unroll
      for (int jj = 0; jj < 4; ++jj) b_[jj] = Bs[k][jj * 16 + tx];
#pragma unroll
      for (int ii = 0; ii < 4; ++ii)
#pragma unroll
        for (int jj = 0; jj < 4; ++jj)
          acc[ii][jj] = fma(a_[ii], b_[jj], acc[ii][jj]);
    }
    __syncthreads();
  }
  for (int ii = 0; ii < 4; ++ii) {
    int i = i0 + ty * 4 + ii;
    for (int jj = 0; jj < 4; ++jj) {
      int j = j0 + jj * 16 + tx;
      double v = 2.0 * acc[ii][jj] - sqA[bg * NN + i] - sqA[bg * NN + j];
      size_t o = ((size_t)bl * NN + i) * MM + j;
      D[o] = v;
      kk[o] = pack_key(v, j);
      T[jj * 16 + tx][ty * 4 + ii] = v;
    }
  }
  if (i0 != j0) {
    __syncthreads();
    for (int rr = 0; rr < 16; ++rr) {
      int li = tid + rr * 256;
      int jrow = li >> 6, il = li & 63;
      double v = T[jrow][il];
      size_t o = ((size_t)bl * NN + j0 + jrow) * MM + i0 + il;
      D[o] = v;
      kk[o] = pack_key(v, i0 + il);
    }
  }
}

// ------- top-20 per row from packed keys; f64 fallback on boundary tie -------
__global__ __launch_bounds__(256) void k_topk(const unsigned* __restrict__ kk,
                                              const double* __restrict__ D,
                                              int* __restrict__ idx, int b0) {
  int wave = threadIdx.x >> 6;
  int lane = threadIdx.x & 63;
  int bl = blockIdx.x;
  int row = blockIdx.y * 4 + wave;
  const unsigned* rp = kk + ((size_t)bl * NN + row) * MM;
  unsigned s[16];
#pragma unroll
  for (int m = 0; m < 16; ++m) s[m] = rp[m * 64 + lane];
  int* op = idx + ((size_t)(b0 + bl) * NN + row) * KNN;
  if (topk20_fast(s, lane, op)) {
    const double* dp = D + ((size_t)bl * NN + row) * MM;
    double v[16];
#pragma unroll
    for (int m = 0; m < 16; ++m) v[m] = dp[m * 64 + lane];
    topk_exact_f64(v, lane, op);
  }
}

// --- fused per-point feature matmul, both modes in one launch (mode = blockIdx.y) ---
// mode 0: out0[b,j,o] = sum_c src0[b,j,c]*w[o,c]        (srcNp=Np0 rows)
// mode 1: out1[b,j,o] = sum_c src1[b,j,c]*(w[o,C+c]-w[o,c])  (NN rows)
__global__ __launch_bounds__(256) void k_featmm2(
    const float* __restrict__ src0, int ld0, int Np0,
    const float* __restrict__ src1, int ld1,
    const float* __restrict__ w, int CW,
    float* __restrict__ out0, float* __restrict__ out1, int C, int O) {
  __shared__ float As[16][68];
  __shared__ float Ws[16][68];
  int nbo = O >> 6;
  int b = blockIdx.x;
  int mode = blockIdx.y >= nbo;
  int o0 = (blockIdx.y - (mode ? nbo : 0)) * 64;
  int j0 = blockIdx.z * 64;
  const float* src = mode ? src1 : src0;
  int lds_ = mode ? ld1 : ld0;
  int Np = mode ? NN : Np0;
  float* out = mode ? out1 : out0;
  int tx = threadIdx.x, ty = threadIdx.y;
  int tid = ty * 16 + tx;
  const float* Sb = src + (size_t)b * Np * lds_;
  float acc[4][4] = {};
  for (int c0 = 0; c0 < C; c0 += 16) {
    for (int r = 0; r < 4; ++r) {
      int li = tid + r * 256;
      int row = li >> 4, k = li & 15;
      int c = c0 + k;
      As[k][row] = (c < C) ? Sb[(size_t)(j0 + row) * lds_ + c] : 0.f;
      float wv = 0.f;
      if (c < C) {
        const float* wr = w + (size_t)(o0 + row) * CW;
        wv = mode == 0 ? wr[c] : (wr[C + c] - wr[c]);
      }
      Ws[k][row] = wv;
    }
    __syncthreads();
#pragma unroll
    for (int k = 0; k < 16; ++k) {
      float a_[4], b_[4];
#pragma unroll
      for (int ii = 0; ii < 4; ++ii) a_[ii] = As[k][ty * 4 + ii];
#pragma unroll
      for (int jj = 0; jj < 4; ++jj) b_[jj] = Ws[k][tx * 4 + jj];
#pragma unroll
      for (int ii = 0; ii < 4; ++ii)
#pragma unroll
        for (int jj = 0; jj < 4; ++jj)
          acc[ii][jj] = fmaf(a_[ii], b_[jj], acc[ii][jj]);
    }
    __syncthreads();
  }
  for (int ii = 0; ii < 4; ++ii) {
    int j = j0 + ty * 4 + ii;
    float4 v;
    float* vp = &v.x;
    for (int jj = 0; jj < 4; ++jj) vp[jj] = acc[ii][jj];
    *(float4*)&out[((size_t)b * Np + j) * O + o0 + tx * 4] = v;
  }
}

// ---- layer-5 GEMM via bf16 MFMA: per-wave 16x16 tile, frags direct from global ----
__global__ __launch_bounds__(256) void k_gemm5_mfma(
    const __hip_bfloat16* __restrict__ cath, const __hip_bfloat16* __restrict__ w5h,
    float* __restrict__ out) {
  int b = blockIdx.x;
  int j0 = blockIdx.y * 16;
  int o0 = blockIdx.z * 64 + (threadIdx.x >> 6) * 16;
  int lane = threadIdx.x & 63;
  int m = lane & 15;
  int quad = lane >> 4;
  const __hip_bfloat16* arow = cath + ((size_t)b * NN + j0 + m) * 512 + quad * 8;
  const __hip_bfloat16* brow = w5h + (size_t)(o0 + m) * 512 + quad * 8;
  f32x4 acc = {0.f, 0.f, 0.f, 0.f};
#pragma unroll
  for (int c0 = 0; c0 < 512; c0 += 32) {
    bf16x8 a = *(const bf16x8*)(arow + c0);
    bf16x8 bb = *(const bf16x8*)(brow + c0);
    acc = __builtin_amdgcn_mfma_f32_16x16x32_bf16(a, bb, acc, 0, 0, 0);
  }
  float* obase = &out[((size_t)b * NN + j0 + quad * 4) * 512 + o0 + m];
#pragma unroll
  for (int r = 0; r < 4; ++r) obase[(size_t)r * 512] = acc[r];
}

// ------- fused gather: per (n,o) compute max_k y, accumulate BN stats; b = blockIdx.x -------
__global__ __launch_bounds__(256) void k_gather(
    const float* __restrict__ u, const float* __restrict__ t, const int* __restrict__ idx,
    double* __restrict__ stats, float* __restrict__ mx, int O, int srcNp) {
  __shared__ int lidx[16 * KNN];
  __shared__ double rs[256];
  __shared__ double rq[256];
  int b = blockIdx.x;
  int n0 = blockIdx.y * 16;
  int o0 = blockIdx.z * 64;
  int tid = threadIdx.x;
  int lane = tid & 63, nsl = tid >> 6;
  for (int w = tid; w < 16 * KNN; w += 256)
    lidx[w] = idx[((size_t)b * NN + n0) * KNN + w];
  __syncthreads();
  int oo = o0 + lane;
  double s1 = 0.0, s2 = 0.0;
  for (int ns = nsl; ns < 16; ns += 4) {
    size_t row = (size_t)b * NN + n0 + ns;
    float tv = t[row * O + oo];
    float mxv = -INFINITY, a1 = 0.f, a2 = 0.f;
#pragma unroll
    for (int k = 0; k < KNN; ++k) {
      int j = lidx[ns * KNN + k];
      float yv = u[((size_t)b * srcNp + j) * O + oo] + tv;
      mxv = fmaxf(mxv, yv);
      a1 += yv;
      a2 = fmaf(yv, yv, a2);
    }
    mx[row * O + oo] = mxv;
    s1 += (double)a1;
    s2 += (double)a2;
  }
  rs[tid] = s1;
  rq[tid] = s2;
  __syncthreads();
  if (tid < 64) {
    s1 = rs[tid] + rs[tid + 64] + rs[tid + 128] + rs[tid + 192];
    s2 = rq[tid] + rq[tid + 64] + rq[tid + 128] + rq[tid + 192];
    atomicAdd(&stats[o0 + tid], s1);
    atomicAdd(&stats[O + o0 + tid], s2);
  }
}

// ---------------- fold BN into per-channel scale/shift ----------------
__global__ void k_bnfin(const double* __restrict__ stats, const float* __restrict__ gamma,
                        const float* __restrict__ beta, float* __restrict__ sc,
                        int O, double cnt) {
  int o = threadIdx.x;
  if (o >= O) return;
  double mean = stats[o] / cnt;
  double var = stats[O + o] / cnt - mean * mean;
  if (var < 0.0) var = 0.0;
  double rstd = 1.0 / sqrt(var + 1e-5);
  float s = gamma[o] * (float)rstd;
  float c = beta[o] - (float)mean * s;
  sc[o] = s;
  sc[O + o] = c;
}

// --- apply BN+lrelu to stored max, write cat slice (f32 + bf16 mirror for L5 MFMA) ---
__global__ __launch_bounds__(256) void k_bnapply(
    const float* __restrict__ mx, const float* __restrict__ u, const float* __restrict__ t,
    const int* __restrict__ idx, const float* __restrict__ sc, float* __restrict__ cat,
    __hip_bfloat16* __restrict__ cath, int coff, int O, int srcNp) {
  int i = blockIdx.x * 256 + threadIdx.x;
  int total = BB * NN * O;
  if (i >= total) return;
  int oo = i % O;
  int n = (i / O) % NN;
  int b = i / (O * NN);
  float s = sc[oo], c = sc[O + oo];
  float v;
  if (s >= 0.f) {
    v = mx[i];
  } else {  // monotone-decreasing transform needs min_k y (never hit with gamma=1)
    float tv = t[i];
    float mn = INFINITY;
    for (int k = 0; k < KNN; ++k) {
      int j = idx[((size_t)b * NN + n) * KNN + k];
      mn = fminf(mn, u[((size_t)b * srcNp + j) * O + oo] + tv);
    }
    v = mn;
  }
  float a = s * v + c;
  a = (a >= 0.f) ? a : NEG_SLOPE * a;
  size_t oidx = ((size_t)b * NN + n) * 512 + coff + oo;
  cat[oidx] = a;
  cath[oidx] = __float2bfloat16(a);
}

// ------- layer 5 streaming stats over stored y5 (B,N,512) -------
__global__ __launch_bounds__(256) void k_stats512(
    const float* __restrict__ y5, double* __restrict__ stats) {
  int b = blockIdx.y;
  int n0 = blockIdx.x * 32;
  int tid = threadIdx.x;
  for (int part = 0; part < 2; ++part) {
    int oo = tid + part * 256;
    float a1 = 0.f, a2 = 0.f;
    for (int ns = 0; ns < 32; ++ns) {
      float v = y5[((size_t)b * NN + n0 + ns) * 512 + oo];
      a1 += v;
      a2 = fmaf(v, v, a2);
    }
    atomicAdd(&stats[oo], (double)a1);
    atomicAdd(&stats[512 + oo], (double)a2);
  }
}

// ------- layer 5 streaming finalize: BN+lrelu on stored y5, transpose, f32 store -------
__global__ __launch_bounds__(256) void k_final5b(
    const float* __restrict__ y5, const float* __restrict__ sc, float* __restrict__ out) {
  __shared__ float tile[64][65];
  int b = blockIdx.z;
  int n0 = blockIdx.x * 64;
  int o0 = blockIdx.y * 64;
  int tid = threadIdx.x;
  for (int r = 0; r < 16; ++r) {
    int li = tid + r * 256;
    int nl = li >> 6, ol = li & 63;
    float v = y5[((size_t)b * NN + n0 + nl) * 512 + o0 + ol];
    float a = sc[o0 + ol] * v + sc[512 + o0 + ol];
    a = (a >= 0.f) ? a : NEG_SLOPE * a;
    tile[nl][ol] = a;
  }
  __syncthreads();
  for (int r = 0; r < 16; ++r) {
    int li = tid + r * 256;
    int ol = li >> 6, nl = li & 63;
    out[((size_t)b * 512 + o0 + ol) * NN + n0 + nl] = tile[nl][ol];
  }
}

// ------- fallback layer 5 (CB<2): GEMM+stats recompute pass -------
__global__ __launch_bounds__(256) void k_mmstats(
    const float* __restrict__ src, const float* __restrict__ w,
    double* __restrict__ stats) {
  __shared__ float As[16][68];
  __shared__ float Ws[16][68];
  __shared__ float redS[16][64];
  __shared__ float redQ[16][64];
  int b = blockIdx.z;
  int j0 = blockIdx.y * 64;
  int o0 = blockIdx.x * 64;
  int tx = threadIdx.x, ty = threadIdx.y;
  int tid = ty * 16 + tx;
  const float* Sb = src + (size_t)b * NN * 512;
  float acc[4][4] = {};
  for (int c0 = 0; c0 < 512; c0 += 16) {
    for (int r = 0; r < 4; ++r) {
      int li = tid + r * 256;
      int row = li >> 4, k = li & 15;
      As[k][row] = Sb[(size_t)(j0 + row) * 512 + c0 + k];
      Ws[k][row] = w[(size_t)(o0 + row) * 512 + c0 + k];
    }
    __syncthreads();
#pragma unroll
    for (int k = 0; k < 16; ++k) {
      float a_[4], b_[4];
#pragma unroll
      for (int ii = 0; ii < 4; ++ii) a_[ii] = As[k][ty * 4 + ii];
#pragma unroll
      for (int jj = 0; jj < 4; ++jj) b_[jj] = Ws[k][tx * 4 + jj];
#pragma unroll
      for (int ii = 0; ii < 4; ++ii)
#pragma unroll
        for (int jj = 0; jj < 4; ++jj)
          acc[ii][jj] = fmaf(a_[ii], b_[jj], acc[ii][jj]);
    }
    __syncthreads();
  }
  for (int jj = 0; jj < 4; ++jj) {
    float s = 0.f, q = 0.f;
    for (int ii = 0; ii < 4; ++ii) { float v = acc[ii][jj]; s += v; q += v * v; }
    redS[ty][tx * 4 + jj] = s;
    redQ[ty][tx * 4 + jj] = q;
  }
  __syncthreads();
  if (tid < 64) {
    float s = 0.f, q = 0.f;
    for (int r = 0; r < 16; ++r) { s += redS[r][tid]; q += redQ[r][tid]; }
    atomicAdd(&stats[o0 + tid], (double)s);
    atomicAdd(&stats[512 + o0 + tid], (double)q);
  }
}

// ------- fallback layer 5 (CB<2): recompute GEMM, BN+lrelu, transposed store -------
__global__ __launch_bounds__(256) void k_final5(
    const float* __restrict__ src, const float* __restrict__ w,
    const float* __restrict__ sc, float* __restrict__ out) {
  __shared__ float As[16][68];
  __shared__ float Ws[16][68];
  __shared__ float tile[64][65];
  int b = blockIdx.z;
  int j0 = blockIdx.y * 64;
  int o0 = blockIdx.x * 64;
  int tx = threadIdx.x, ty = threadIdx.y;
  int tid = ty * 16 + tx;
  const float* Sb = src + (size_t)b * NN * 512;
  float acc[4][4] = {};
  for (int c0 = 0; c0 < 512; c0 += 16) {
    for (int r = 0; r < 4; ++r) {
      int li = tid + r * 256;
      int row = li >> 4, k = li & 15;
      As[k][row] = Sb[(size_t)(j0 + row) * 512 + c0 + k];
      Ws[k][row] = w[(size_t)(o0 + row) * 512 + c0 + k];
    }
    __syncthreads();
#pragma unroll
    for (int k = 0; k < 16; ++k) {
      float a_[4], b_[4];
#pragma unroll
      for (int ii = 0; ii < 4; ++ii) a_[ii] = As[k][ty * 4 + ii];
#pragma unroll
      for (int jj = 0; jj < 4; ++jj) b_[jj] = Ws[k][tx * 4 + jj];
#pragma unroll
      for (int ii = 0; ii < 4; ++ii)
#pragma unroll
        for (int jj = 0; jj < 4; ++jj)
          acc[ii][jj] = fmaf(a_[ii], b_[jj], acc[ii][jj]);
    }
    __syncthreads();
  }
  for (int ii = 0; ii < 4; ++ii)
    for (int jj = 0; jj < 4; ++jj) {
      int nl = ty * 4 + ii, ol = tx * 4 + jj;
      float a = sc[o0 + ol] * acc[ii][jj] + sc[512 + o0 + ol];
      a = (a >= 0.f) ? a : NEG_SLOPE * a;
      tile[nl][ol] = a;
    }
  __syncthreads();
  for (int r = 0; r < 16; ++r) {
    int li = tid + r * 256;
    int ol = li >> 6, nl = li & 63;
    out[((size_t)b * 512 + o0 + ol) * NN + j0 + nl] = tile[nl][ol];
  }
}

// =====================================================================================
// r13: (1) LDS pad fixes in gram kernels (136/72/68 -> 137/73/69; staging writes were
// 4-way bank-conflicted: 4.7e6/dispatch in r12); (2) gram epilogue writes packed u32
// keys next to DD -> k_topk fast path reads half the bytes and skips per-element pack,
// f64 fallback reads DD only on boundary ties; (3) featmm mode0+mode1 fused per layer.
extern "C" void kernel_launch(void* const* d_in, const int* in_sizes, int n_in,
                              void* d_out, int out_size, void* d_ws, size_t ws_size,
                              hipStream_t stream) {
  const float* x = (const float*)d_in[0];
  const float* y = (const float*)d_in[1];
  const float* w1 = (const float*)d_in[2];
  const float* w2 = (const float*)d_in[3];
  const float* w3 = (const float*)d_in[4];
  const float* w4 = (const float*)d_in[5];
  const float* w5 = (const float*)d_in[6];
  const float* g1 = (const float*)d_in[7];
  const float* b1 = (const float*)d_in[8];
  const float* g2 = (const float*)d_in[9];
  const float* b2 = (const float*)d_in[10];
  const float* g3 = (const float*)d_in[11];
  const float* b3 = (const float*)d_in[12];
  const float* g4 = (const float*)d_in[13];
  const float* b4 = (const float*)d_in[14];
  const float* g5 = (const float*)d_in[15];
  const float* b5 = (const float*)d_in[16];

  char* base = (char*)d_ws;
  size_t off = 0;
  auto alloc = [&](size_t bytes) -> char* {
    char* p = base + off;
    off += (bytes + 255) & ~(size_t)255;
    return p;
  };
  double* st = (double*)alloc(1024 * 8);
  float* sc  = (float*)alloc(1024 * 4);
  double* sq  = (double*)alloc((size_t)BB * NN * 8);
  double* rnx = (double*)alloc((size_t)BB * NN * 8);
  double* rny = (double*)alloc((size_t)BB * MM * 8);
  int*   idxb = (int*)alloc((size_t)BB * NN * KNN * 4);
  float* xs3 = (float*)alloc((size_t)BB * NN * 3 * 4);
  float* ys  = (float*)alloc((size_t)BB * MM * 128 * 4);
  float* cat = (float*)alloc((size_t)BB * NN * 512 * 4);
  __hip_bfloat16* cath = (__hip_bfloat16*)alloc((size_t)BB * NN * 512 * 2);
  __hip_bfloat16* w5h  = (__hip_bfloat16*)alloc((size_t)512 * 512 * 2);
  size_t ddBatchBytes = (size_t)NN * MM * 8;  // 8 MB per batch (f64)
  size_t kkBatchBytes = (size_t)NN * MM * 4;  // 4 MB per batch (keys)
  size_t avail = (ws_size > off) ? (ws_size - off) : 0;
  int CB = (int)(avail / (ddBatchBytes + kkBatchBytes));
  if (CB < 1) CB = 1;
  if (CB > BB) CB = BB;
  char*  U   = alloc((size_t)CB * ddBatchBytes);
  unsigned* KK = (unsigned*)alloc((size_t)CB * kkBatchBytes);
  double* DD = (double*)U;                     // dist/simi chunk (f64), dead after topk
  float* tt  = (float*)U;                      // center term (f32, <=8MB), after DD dead
  float* y5  = (float*)U;                      // layer-5 pre-BN (16MB, needs CB>=2)
  float* uu  = (float*)d_out;                  // source term (<=8MB)
  float* mx  = (float*)d_out + (size_t)2 * 1024 * 1024;  // max_k y (<=8MB)
  float* outp = (float*)d_out;

  const dim3 blk2(16, 16);
  const double cntE = (double)BB * NN * KNN;

  // knn: sym=1 -> triangular symmetric euclid gram (A==B); else general 128x64 MODE
  auto knn = [&](const float* A, int lda, const float* Bm, int ldb,
                 const double* sa, const double* sb, int C, int mode, int sym) {
    for (int b0 = 0; b0 < BB; b0 += CB) {
      int cb = (BB - b0 < CB) ? (BB - b0) : CB;
      if (sym) {
        k_gram_sym<<<dim3(cb, 136), blk2, 0, stream>>>(A, lda, sa, DD, KK, C, b0);
      } else {
        dim3 g(cb, MM / 64, NN / 128);
        if (mode == 1)
          k_gram2<1><<<g, blk2, 0, stream>>>(A, lda, Bm, ldb, sa, sb, DD, KK, C, b0);
        else
          k_gram2<2><<<g, blk2, 0, stream>>>(A, lda, Bm, ldb, sa, sb, DD, KK, C, b0);
      }
      k_topk<<<dim3(cb, 256), 256, 0, stream>>>(KK, DD, idxb, b0);
    }
  };

  auto edge_layer = [&](const float* ctr, int ldc, const float* src, int ldsrc, int srcNp,
                        const float* w, int CW, const float* g, const float* bb,
                        int C, int O, int coff) {
    k_featmm2<<<dim3(8, 2 * (O / 64), 16), blk2, 0, stream>>>(src, ldsrc, srcNp, ctr, ldc,
                                                              w, CW, uu, tt, C, O);
    hipMemsetAsync(st, 0, 1024 * 8, stream);
    k_gather<<<dim3(BB, NN / 16, O / 64), 256, 0, stream>>>(uu, tt, idxb, st, mx, O, srcNp);
    k_bnfin<<<1, O, 0, stream>>>(st, g, bb, sc, O, cntE);
    k_bnapply<<<(BB * NN * O + 255) / 256, 256, 0, stream>>>(mx, uu, tt, idxb, sc, cat,
                                                             cath, coff, O, srcNp);
  };

  // ---- input transposes + w5 bf16 convert ----
  k_transpose<<<96, 256, 0, stream>>>(x, xs3, 3, NN);
  k_transpose<<<2048, 256, 0, stream>>>(y, ys, 128, MM);
  k_cvt_bf16<<<1024, 256, 0, stream>>>(w5, w5h, 512 * 512);

  // ---- layer 1: C=3, O=64 (fused knn, no DD) ----
  k_rowsq<0><<<32, 256, 0, stream>>>(xs3, 3, 3, sq);
  k_knn3<<<dim3(BB, 256), 256, 0, stream>>>(xs3, sq, idxb);
  edge_layer(xs3, 3, xs3, 3, NN, w1, 6, g1, b1, 3, 64, 0);

  // ---- layer 2: x1 = cat[:,0:64], C=64, O=64 ----
  k_rowsq<0><<<32, 256, 0, stream>>>(cat, 512, 64, sq);
  knn(cat, 512, cat, 512, sq, sq, 64, 1, 1);
  edge_layer(cat, 512, cat, 512, NN, w2, 128, g2, b2, 64, 64, 64);

  // ---- layer 3: x2 = cat[:,64:128], C=64, O=128 ----
  k_rowsq<0><<<32, 256, 0, stream>>>(cat + 64, 512, 64, sq);
  knn(cat + 64, 512, cat + 64, 512, sq, sq, 64, 1, 1);
  edge_layer(cat + 64, 512, cat + 64, 512, NN, w3, 128, g3, b3, 64, 128, 128);

  // ---- layer 4 (IA): x3 = cat[:,128:256], src = y (cosine knn), C=128, O=256 ----
  k_rowsq<1><<<32, 256, 0, stream>>>(cat + 128, 512, 128, rnx);
  k_rowsq<1><<<32, 256, 0, stream>>>(ys, 128, 128, rny);
  knn(cat + 128, 512, ys, 128, rnx, rny, 128, 2, 0);
  edge_layer(cat + 128, 512, ys, 128, MM, w4, 256, g4, b4, 128, 256, 256);

  // ---- layer 5: bf16-MFMA GEMM -> y5, BN over (B,N), lrelu, transposed out ----
  hipMemsetAsync(st, 0, 1024 * 8, stream);
  if (CB >= 2) {
    k_gemm5_mfma<<<dim3(BB, 64, 8), 256, 0, stream>>>(cath, w5h, y5);
    k_stats512<<<dim3(32, 8), 256, 0, stream>>>(y5, st);
    k_bnfin<<<1, 512, 0, stream>>>(st, g5, b5, sc, 512, (double)(BB * NN));
    k_final5b<<<dim3(16, 8, 8), 256, 0, stream>>>(y5, sc, outp);
  } else {
    k_mmstats<<<dim3(8, 16, 8), blk2, 0, stream>>>(cat, w5, st);
    k_bnfin<<<1, 512, 0, stream>>>(st, g5, b5, sc, 512, (double)(BB * NN));
    k_final5<<<dim3(8, 16, 8), blk2, 0, stream>>>(cat, w5, sc, outp);
  }
}